// Round 9
// baseline (286.109 us; speedup 1.0000x reference)
//
#include <hip/hip_runtime.h>

#define NUM_USERS 100000
#define NUM_ITEMS 200000
#define NNODES    300000   // NUM_USERS + NUM_ITEMS
#define EDIM      64
#define NEDGES    1200000
#define BATCH     4096
#define CHUNK     1024
#define NCHUNKS   ((NNODES + CHUNK - 1) / CHUNK)   // 293

static inline size_t align256(size_t x) { return (x + 255) & ~(size_t)255; }

__device__ __forceinline__ void f4add(float4& a, const float4& b) {
    a.x += b.x; a.y += b.y; a.z += b.z; a.w += b.w;
}

// ---------------- marking + CSR build (2 fused edge passes) ----------------

__global__ void mark_sampled_k(const int* __restrict__ users, const int* __restrict__ items,
                               unsigned char* __restrict__ mS) {
    int t = (int)(blockIdx.x * blockDim.x + threadIdx.x);
    if (t >= 2 * BATCH) return;
    int node = (t < BATCH) ? users[t] : (NUM_USERS + items[t - BATCH]);
    mS[node] = 1;
}

// Pass 1 over edges: histogram counts[dst] + markA (mA[src]=1 if dst sampled).
__global__ void histA_k(const int* __restrict__ src, const int* __restrict__ dst,
                        int* __restrict__ counts, const unsigned char* __restrict__ mS,
                        unsigned char* __restrict__ mA) {
    int e = (int)(blockIdx.x * blockDim.x + threadIdx.x);
    if (e >= NEDGES) return;
    int d = dst[e];
    atomicAdd(&counts[d], 1);
    if (mS[d]) mA[src[e]] = 1;
}

__global__ void scan_chunk_k(const int* __restrict__ counts, int* __restrict__ row_ptr,
                             int* __restrict__ chunk_tot) {
    __shared__ int sm[256];
    int t = threadIdx.x;
    int base = (int)blockIdx.x * CHUNK + t * 4;
    int v0 = (base + 0 < NNODES) ? counts[base + 0] : 0;
    int v1 = (base + 1 < NNODES) ? counts[base + 1] : 0;
    int v2 = (base + 2 < NNODES) ? counts[base + 2] : 0;
    int v3 = (base + 3 < NNODES) ? counts[base + 3] : 0;
    int ts = v0 + v1 + v2 + v3;
    sm[t] = ts;
    __syncthreads();
    for (int off = 1; off < 256; off <<= 1) {
        int x = (t >= off) ? sm[t - off] : 0;
        __syncthreads();
        sm[t] += x;
        __syncthreads();
    }
    int run = sm[t] - ts;
    if (t == 255) chunk_tot[blockIdx.x] = sm[255];
    if (base + 0 < NNODES) row_ptr[base + 0] = run; run += v0;
    if (base + 1 < NNODES) row_ptr[base + 1] = run; run += v1;
    if (base + 2 < NNODES) row_ptr[base + 2] = run; run += v2;
    if (base + 3 < NNODES) row_ptr[base + 3] = run;
}

// 64-lane shfl scan of the 293 chunk totals (exclusive, in-place).
__global__ void scan_tops_k(int* __restrict__ chunk_tot, int* __restrict__ row_ptr) {
    int lane = threadIdx.x & 63;
    int carry = 0;
    for (int base = 0; base < NCHUNKS; base += 64) {
        int idx = base + lane;
        int v = (idx < NCHUNKS) ? chunk_tot[idx] : 0;
        int x = v;
        #pragma unroll
        for (int off = 1; off < 64; off <<= 1) {
            int t = __shfl_up(x, off, 64);
            if (lane >= off) x += t;
        }
        if (idx < NCHUNKS) chunk_tot[idx] = carry + x - v;   // exclusive
        carry += __shfl(x, 63, 64);
    }
    if (lane == 0) row_ptr[NNODES] = carry;
}

__global__ void add_off_k(int* __restrict__ row_ptr, const int* __restrict__ chunk_tot) {
    int i = (int)(blockIdx.x * blockDim.x + threadIdx.x);
    if (i < NNODES) row_ptr[i] += chunk_tot[i / CHUNK];
}

// Pass 2 over edges: CSR fill + markB (mB[src]=1 if dst in mS|mA).
__global__ void fillB_k(const int* __restrict__ src, const int* __restrict__ dst,
                        const int* __restrict__ row_ptr, int* __restrict__ cursor,
                        int* __restrict__ ssrc, const unsigned char* __restrict__ mS,
                        const unsigned char* __restrict__ mA, unsigned char* __restrict__ mB) {
    int e = (int)(blockIdx.x * blockDim.x + threadIdx.x);
    if (e >= NEDGES) return;
    int d = dst[e];
    int s = src[e];
    int pos = atomicAdd(&cursor[d], 1);
    ssrc[row_ptr[d] + pos] = s;
    if (mS[d] | mA[d]) mB[s] = 1;
}

// Compact active sets into worklists. Wave-aggregated: ONE atomic per wave
// per list (r8's per-thread atomics on a single counter serialized -> 109us).
// Order within/across waves nondeterministic; per-node output is
// order-independent => bitwise deterministic results.
__global__ void build_wl_k(const unsigned char* __restrict__ mS, const unsigned char* __restrict__ mA,
                           const unsigned char* __restrict__ mB, int* __restrict__ wl1,
                           int* __restrict__ wl2, int* __restrict__ wl_n) {
    int i = (int)(blockIdx.x * blockDim.x + threadIdx.x);
    int lane = threadIdx.x & 63;
    unsigned char s = 0, a = 0, b = 0;
    if (i < NNODES) { s = mS[i]; a = mA[i]; b = mB[i]; }
    bool p1 = (i < NNODES) && (s | a | b);
    bool p2 = (i < NNODES) && (s | a);
    unsigned long long lt = (lane == 63) ? ~0ULL >> 1 : ((1ULL << lane) - 1);

    unsigned long long b1 = __ballot(p1);
    if (b1) {
        int leader = __ffsll((long long)b1) - 1;
        int base = 0;
        if (lane == leader) base = atomicAdd(&wl_n[0], __popcll(b1));
        base = __shfl(base, leader, 64);
        if (p1) wl1[base + __popcll(b1 & lt)] = i;
    }
    unsigned long long b2 = __ballot(p2);
    if (b2) {
        int leader = __ffsll((long long)b2) - 1;
        int base = 0;
        if (lane == leader) base = atomicAdd(&wl_n[1], __popcll(b2));
        base = __shfl(base, leader, 64);
        if (p2) wl2[base + __popcll(b2 & lt)] = i;
    }
}

// ---------------- propagation: worklist grid-stride, float4 x 4 edge slots ----------------

#define PROP_BLOCKS 2048   // 8192 waves

__global__ __launch_bounds__(256) void prop_f4_k(
        const float* __restrict__ cur, float* __restrict__ nxt,
        const int* __restrict__ row_ptr, const int* __restrict__ ssrc,
        const int* __restrict__ wl, const int* __restrict__ wl_n) {
    int lane = threadIdx.x & 63;
    int sub = lane >> 4, d16 = lane & 15;
    int gw = (int)((blockIdx.x * blockDim.x + threadIdx.x) >> 6);
    int nw = (int)((gridDim.x * blockDim.x) >> 6);
    int n = wl_n[0];
    const float4* cur4 = (const float4*)cur;
    for (int i = gw; i < n; i += nw) {
        int node = wl[i];
        int s0 = row_ptr[node], s1 = row_ptr[node + 1];
        float4 acc0 = {0.f, 0.f, 0.f, 0.f}, acc1 = {0.f, 0.f, 0.f, 0.f};
        int e = s0;
        for (; e + 8 <= s1; e += 8) {
            int i0 = ssrc[e + sub];
            int i1 = ssrc[e + 4 + sub];
            float4 v0 = cur4[(size_t)i0 * 16 + d16];
            float4 v1 = cur4[(size_t)i1 * 16 + d16];
            f4add(acc0, v0);
            f4add(acc1, v1);
        }
        int ee0 = e + sub;
        if (ee0 < s1) f4add(acc0, cur4[(size_t)ssrc[ee0] * 16 + d16]);
        int ee1 = e + 4 + sub;
        if (ee1 < s1) f4add(acc1, cur4[(size_t)ssrc[ee1] * 16 + d16]);
        f4add(acc0, acc1);
        acc0.x += __shfl_xor(acc0.x, 16, 64); acc0.x += __shfl_xor(acc0.x, 32, 64);
        acc0.y += __shfl_xor(acc0.y, 16, 64); acc0.y += __shfl_xor(acc0.y, 32, 64);
        acc0.z += __shfl_xor(acc0.z, 16, 64); acc0.z += __shfl_xor(acc0.z, 32, 64);
        acc0.w += __shfl_xor(acc0.w, 16, 64); acc0.w += __shfl_xor(acc0.w, 32, 64);
        if (sub == 0) ((float4*)nxt)[(size_t)node * 16 + d16] = acc0;
    }
}

// Fused: accs[w] = emb+bufA+bufB at sampled node + layer-3 gather of bufB.
__global__ __launch_bounds__(256) void final_acc_k(
        const float* __restrict__ emb, const float* __restrict__ bufA,
        const float* __restrict__ bufB, const int* __restrict__ users,
        const int* __restrict__ items, const int* __restrict__ row_ptr,
        const int* __restrict__ ssrc, float* __restrict__ accs) {
    int t = (int)(blockIdx.x * blockDim.x + threadIdx.x);
    int w = t >> 6;
    int lane = threadIdx.x & 63, sub = lane >> 4, d16 = lane & 15;
    if (w >= 2 * BATCH) return;
    int node = (w < BATCH) ? users[w] : (NUM_USERS + items[w - BATCH]);
    int s0 = row_ptr[node], s1 = row_ptr[node + 1];
    const float4* b4 = (const float4*)bufB;
    float4 acc0 = {0.f, 0.f, 0.f, 0.f}, acc1 = {0.f, 0.f, 0.f, 0.f};
    int e = s0;
    for (; e + 8 <= s1; e += 8) {
        int i0 = ssrc[e + sub];
        int i1 = ssrc[e + 4 + sub];
        f4add(acc0, b4[(size_t)i0 * 16 + d16]);
        f4add(acc1, b4[(size_t)i1 * 16 + d16]);
    }
    int ee0 = e + sub;
    if (ee0 < s1) f4add(acc0, b4[(size_t)ssrc[ee0] * 16 + d16]);
    int ee1 = e + 4 + sub;
    if (ee1 < s1) f4add(acc1, b4[(size_t)ssrc[ee1] * 16 + d16]);
    f4add(acc0, acc1);
    acc0.x += __shfl_xor(acc0.x, 16, 64); acc0.x += __shfl_xor(acc0.x, 32, 64);
    acc0.y += __shfl_xor(acc0.y, 16, 64); acc0.y += __shfl_xor(acc0.y, 32, 64);
    acc0.z += __shfl_xor(acc0.z, 16, 64); acc0.z += __shfl_xor(acc0.z, 32, 64);
    acc0.w += __shfl_xor(acc0.w, 16, 64); acc0.w += __shfl_xor(acc0.w, 32, 64);
    if (sub == 0) {
        size_t ro = (size_t)node * 16 + d16;
        float4 ev = ((const float4*)emb)[ro];
        float4 av = ((const float4*)bufA)[ro];
        float4 bv = ((const float4*)bufB)[ro];
        float4 r;
        r.x = ev.x + av.x + bv.x + acc0.x;
        r.y = ev.y + av.y + bv.y + acc0.y;
        r.z = ev.z + av.z + bv.z + acc0.z;
        r.w = ev.w + av.w + bv.w + acc0.w;
        ((float4*)accs)[(size_t)w * 16 + d16] = r;
    }
}

__global__ void dot_out_k(const float* __restrict__ accs, float* __restrict__ out) {
    int t = (int)(blockIdx.x * blockDim.x + threadIdx.x);
    int b = t >> 6, lane = t & 63;
    if (b >= BATCH) return;
    float p = accs[(size_t)b * EDIM + lane] * accs[(size_t)(BATCH + b) * EDIM + lane];
    #pragma unroll
    for (int off = 32; off; off >>= 1) p += __shfl_down(p, off, 64);
    if (lane == 0) out[b] = p * (1.0f / 16.0f);
}

// ---------------- fallback (baseline atomic path) ----------------

__global__ void acc_batch_k(const float* __restrict__ cur, const int* __restrict__ users,
                            const int* __restrict__ items, float* __restrict__ accs, int first) {
    int t = (int)(blockIdx.x * blockDim.x + threadIdx.x);
    int row = t >> 6, lane = t & 63;
    if (row >= 2 * BATCH) return;
    int node = (row < BATCH) ? users[row] : (NUM_USERS + items[row - BATCH]);
    float v = cur[(size_t)node * EDIM + lane];
    size_t o = (size_t)row * EDIM + lane;
    if (first) accs[o] = v;
    else       accs[o] += v;
}

__global__ void scatter_add_k(const float* __restrict__ cur, float* __restrict__ nxt,
                              const int* __restrict__ src, const int* __restrict__ dst) {
    int w = (int)((blockIdx.x * blockDim.x + threadIdx.x) >> 6);
    int lane = threadIdx.x & 63;
    if (w >= NEDGES) return;
    float v = cur[(size_t)src[w] * EDIM + lane];
    atomicAdd(&nxt[(size_t)dst[w] * EDIM + lane], v);
}

extern "C" void kernel_launch(void* const* d_in, const int* in_sizes, int n_in,
                              void* d_out, int out_size, void* d_ws, size_t ws_size,
                              hipStream_t stream) {
    const float* emb   = (const float*)d_in[0];
    const int*   edge  = (const int*)d_in[1];
    const int*   src   = edge;            // edge_index[0]
    const int*   dst   = edge + NEDGES;   // edge_index[1]
    const int*   users = (const int*)d_in[2];
    const int*   items = (const int*)d_in[3];
    float*       out   = (float*)d_out;

    const size_t bufBytes = (size_t)NNODES * EDIM * sizeof(float); // 76.8 MB

    // workspace layout (zero-region is contiguous: one memset)
    size_t off = 0;
    float* bufA = (float*)((char*)d_ws + off); off = align256(off + bufBytes);
    float* bufB = (float*)((char*)d_ws + off); off = align256(off + bufBytes);
    float* accs = (float*)((char*)d_ws + off); off = align256(off + (size_t)2 * BATCH * EDIM * sizeof(float));
    int* row_ptr = (int*)((char*)d_ws + off); off = align256(off + (size_t)(NNODES + 1) * sizeof(int));
    int* ssrc    = (int*)((char*)d_ws + off); off = align256(off + (size_t)NEDGES * sizeof(int));
    int* wl1     = (int*)((char*)d_ws + off); off = align256(off + (size_t)NNODES * sizeof(int));
    int* wl2     = (int*)((char*)d_ws + off); off = align256(off + (size_t)NNODES * sizeof(int));
    const size_t zeroBase = off;
    int* counts    = (int*)((char*)d_ws + off); off += (size_t)NNODES * sizeof(int);
    int* cursor    = (int*)((char*)d_ws + off); off += (size_t)NNODES * sizeof(int);
    int* chunk_tot = (int*)((char*)d_ws + off); off += (size_t)NCHUNKS * sizeof(int);
    int* wl_n      = (int*)((char*)d_ws + off); off += 2 * sizeof(int);
    unsigned char* mS = (unsigned char*)((char*)d_ws + off); off += (size_t)NNODES;
    unsigned char* mA = (unsigned char*)((char*)d_ws + off); off += (size_t)NNODES;
    unsigned char* mB = (unsigned char*)((char*)d_ws + off); off += (size_t)NNODES;
    const size_t zeroBytes = off - zeroBase;
    const size_t needed = align256(off);

    const dim3 blk(256);
    const int edgeBlocks = (NEDGES + 255) / 256;
    const int nodeBlocks = (NNODES + 255) / 256;
    const int sampBlocks = (2 * BATCH * 64 + 255) / 256;
    const int dotBlocks  = (BATCH * 64 + 255) / 256;

    if (ws_size >= needed) {
        hipMemsetAsync((char*)d_ws + zeroBase, 0, zeroBytes, stream);
        mark_sampled_k<<<(2 * BATCH + 255) / 256, blk, 0, stream>>>(users, items, mS);
        histA_k<<<edgeBlocks, blk, 0, stream>>>(src, dst, counts, mS, mA);
        scan_chunk_k<<<NCHUNKS, blk, 0, stream>>>(counts, row_ptr, chunk_tot);
        scan_tops_k<<<1, 64, 0, stream>>>(chunk_tot, row_ptr);
        add_off_k<<<nodeBlocks, blk, 0, stream>>>(row_ptr, chunk_tot);
        fillB_k<<<edgeBlocks, blk, 0, stream>>>(src, dst, row_ptr, cursor, ssrc, mS, mA, mB);
        build_wl_k<<<nodeBlocks, blk, 0, stream>>>(mS, mA, mB, wl1, wl2, wl_n);

        prop_f4_k<<<PROP_BLOCKS, blk, 0, stream>>>(emb,  bufA, row_ptr, ssrc, wl1, wl_n);      // layer 1
        prop_f4_k<<<PROP_BLOCKS, blk, 0, stream>>>(bufA, bufB, row_ptr, ssrc, wl2, wl_n + 1);  // layer 2
        final_acc_k<<<sampBlocks, blk, 0, stream>>>(emb, bufA, bufB, users, items, row_ptr, ssrc, accs);
        dot_out_k<<<dotBlocks, blk, 0, stream>>>(accs, out);
    } else {
        // ---- fallback: baseline atomic path ----
        const int scatterBlocks = (NEDGES + 3) / 4;
        acc_batch_k<<<sampBlocks, blk, 0, stream>>>(emb, users, items, accs, 1);
        const float* cur = emb;
        float* bufs[2] = {bufA, bufB};
        for (int l = 0; l < 3; ++l) {
            float* nxt = bufs[l & 1];
            hipMemsetAsync(nxt, 0, bufBytes, stream);
            scatter_add_k<<<scatterBlocks, blk, 0, stream>>>(cur, nxt, src, dst);
            acc_batch_k<<<sampBlocks, blk, 0, stream>>>(nxt, users, items, accs, 0);
            cur = nxt;
        }
        dot_out_k<<<dotBlocks, blk, 0, stream>>>(accs, out);
    }
}

// Round 10
// 205.856 us; speedup vs baseline: 1.3899x; 1.3899x over previous
//
#include <hip/hip_runtime.h>

#define NUM_USERS 100000
#define NUM_ITEMS 200000
#define NNODES    300000   // NUM_USERS + NUM_ITEMS
#define EDIM      64
#define NEDGES    1200000
#define BATCH     4096
#define CHUNK     1024
#define NCHUNKS   ((NNODES + CHUNK - 1) / CHUNK)   // 293

static inline size_t align256(size_t x) { return (x + 255) & ~(size_t)255; }

__device__ __forceinline__ void f4add(float4& a, const float4& b) {
    a.x += b.x; a.y += b.y; a.z += b.z; a.w += b.w;
}

// ---------------- marking + CSR build (2 fused edge passes) ----------------

__global__ void mark_sampled_k(const int* __restrict__ users, const int* __restrict__ items,
                               unsigned char* __restrict__ mS) {
    int t = (int)(blockIdx.x * blockDim.x + threadIdx.x);
    if (t >= 2 * BATCH) return;
    int node = (t < BATCH) ? users[t] : (NUM_USERS + items[t - BATCH]);
    mS[node] = 1;
}

// Pass 1 over edges: histogram counts[dst] + markA (mA[src]=1 if dst sampled).
__global__ void histA_k(const int* __restrict__ src, const int* __restrict__ dst,
                        int* __restrict__ counts, const unsigned char* __restrict__ mS,
                        unsigned char* __restrict__ mA) {
    int e = (int)(blockIdx.x * blockDim.x + threadIdx.x);
    if (e >= NEDGES) return;
    int d = dst[e];
    atomicAdd(&counts[d], 1);
    if (mS[d]) mA[src[e]] = 1;
}

__global__ void scan_chunk_k(const int* __restrict__ counts, int* __restrict__ row_ptr,
                             int* __restrict__ chunk_tot) {
    __shared__ int sm[256];
    int t = threadIdx.x;
    int base = (int)blockIdx.x * CHUNK + t * 4;
    int v0 = (base + 0 < NNODES) ? counts[base + 0] : 0;
    int v1 = (base + 1 < NNODES) ? counts[base + 1] : 0;
    int v2 = (base + 2 < NNODES) ? counts[base + 2] : 0;
    int v3 = (base + 3 < NNODES) ? counts[base + 3] : 0;
    int ts = v0 + v1 + v2 + v3;
    sm[t] = ts;
    __syncthreads();
    for (int off = 1; off < 256; off <<= 1) {
        int x = (t >= off) ? sm[t - off] : 0;
        __syncthreads();
        sm[t] += x;
        __syncthreads();
    }
    int run = sm[t] - ts;
    if (t == 255) chunk_tot[blockIdx.x] = sm[255];
    if (base + 0 < NNODES) row_ptr[base + 0] = run; run += v0;
    if (base + 1 < NNODES) row_ptr[base + 1] = run; run += v1;
    if (base + 2 < NNODES) row_ptr[base + 2] = run; run += v2;
    if (base + 3 < NNODES) row_ptr[base + 3] = run;
}

// 64-lane shfl scan of the 293 chunk totals (exclusive, in-place).
__global__ void scan_tops_k(int* __restrict__ chunk_tot, int* __restrict__ row_ptr) {
    int lane = threadIdx.x & 63;
    int carry = 0;
    for (int base = 0; base < NCHUNKS; base += 64) {
        int idx = base + lane;
        int v = (idx < NCHUNKS) ? chunk_tot[idx] : 0;
        int x = v;
        #pragma unroll
        for (int off = 1; off < 64; off <<= 1) {
            int t = __shfl_up(x, off, 64);
            if (lane >= off) x += t;
        }
        if (idx < NCHUNKS) chunk_tot[idx] = carry + x - v;   // exclusive
        carry += __shfl(x, 63, 64);
    }
    if (lane == 0) row_ptr[NNODES] = carry;
}

__global__ void add_off_k(int* __restrict__ row_ptr, const int* __restrict__ chunk_tot) {
    int i = (int)(blockIdx.x * blockDim.x + threadIdx.x);
    if (i < NNODES) row_ptr[i] += chunk_tot[i / CHUNK];
}

// Pass 2 over edges: CSR fill + markB (mB[src]=1 if dst in mS|mA).
__global__ void fillB_k(const int* __restrict__ src, const int* __restrict__ dst,
                        const int* __restrict__ row_ptr, int* __restrict__ cursor,
                        int* __restrict__ ssrc, const unsigned char* __restrict__ mS,
                        const unsigned char* __restrict__ mA, unsigned char* __restrict__ mB) {
    int e = (int)(blockIdx.x * blockDim.x + threadIdx.x);
    if (e >= NEDGES) return;
    int d = dst[e];
    int s = src[e];
    int pos = atomicAdd(&cursor[d], 1);
    ssrc[row_ptr[d] + pos] = s;
    if (mS[d] | mA[d]) mB[s] = 1;
}

// Fold masks into 2-bit flags: bit0 = layer1-active (mS|mA|mB),
// bit1 = layer2-active (mS|mA). No atomics, no shared counters
// (r8/r9's single-counter compaction serialized at the coherence
// point for 109us regardless of wave-aggregation).
__global__ void combine_k(const unsigned char* __restrict__ mS, const unsigned char* __restrict__ mA,
                          const unsigned char* __restrict__ mB, unsigned char* __restrict__ need) {
    int i = (int)(blockIdx.x * blockDim.x + threadIdx.x);
    if (i >= NNODES) return;
    unsigned char s = mS[i], a = mA[i], b = mB[i];
    need[i] = (unsigned char)(((s | a | b) ? 1 : 0) | ((s | a) ? 2 : 0));
}

// ---------------- propagation: flag-gated grid-stride, float4 x 4 edge slots ----------------

#define PROP_BLOCKS 2048   // 8192 waves

__global__ __launch_bounds__(256) void prop_f4_k(
        const float* __restrict__ cur, float* __restrict__ nxt,
        const int* __restrict__ row_ptr, const int* __restrict__ ssrc,
        const unsigned char* __restrict__ need, int bit) {
    int lane = threadIdx.x & 63;
    int sub = lane >> 4, d16 = lane & 15;
    int gw = (int)((blockIdx.x * blockDim.x + threadIdx.x) >> 6);
    int nw = (int)((gridDim.x * blockDim.x) >> 6);
    const float4* cur4 = (const float4*)cur;
    for (int node = gw; node < NNODES; node += nw) {
        if (!(need[node] & bit)) continue;
        int s0 = row_ptr[node], s1 = row_ptr[node + 1];
        float4 acc0 = {0.f, 0.f, 0.f, 0.f}, acc1 = {0.f, 0.f, 0.f, 0.f};
        int e = s0;
        for (; e + 8 <= s1; e += 8) {
            int i0 = ssrc[e + sub];
            int i1 = ssrc[e + 4 + sub];
            float4 v0 = cur4[(size_t)i0 * 16 + d16];
            float4 v1 = cur4[(size_t)i1 * 16 + d16];
            f4add(acc0, v0);
            f4add(acc1, v1);
        }
        int ee0 = e + sub;
        if (ee0 < s1) f4add(acc0, cur4[(size_t)ssrc[ee0] * 16 + d16]);
        int ee1 = e + 4 + sub;
        if (ee1 < s1) f4add(acc1, cur4[(size_t)ssrc[ee1] * 16 + d16]);
        f4add(acc0, acc1);
        acc0.x += __shfl_xor(acc0.x, 16, 64); acc0.x += __shfl_xor(acc0.x, 32, 64);
        acc0.y += __shfl_xor(acc0.y, 16, 64); acc0.y += __shfl_xor(acc0.y, 32, 64);
        acc0.z += __shfl_xor(acc0.z, 16, 64); acc0.z += __shfl_xor(acc0.z, 32, 64);
        acc0.w += __shfl_xor(acc0.w, 16, 64); acc0.w += __shfl_xor(acc0.w, 32, 64);
        if (sub == 0) ((float4*)nxt)[(size_t)node * 16 + d16] = acc0;
    }
}

// Fused: accs[w] = emb+bufA+bufB at sampled node + layer-3 gather of bufB.
__global__ __launch_bounds__(256) void final_acc_k(
        const float* __restrict__ emb, const float* __restrict__ bufA,
        const float* __restrict__ bufB, const int* __restrict__ users,
        const int* __restrict__ items, const int* __restrict__ row_ptr,
        const int* __restrict__ ssrc, float* __restrict__ accs) {
    int t = (int)(blockIdx.x * blockDim.x + threadIdx.x);
    int w = t >> 6;
    int lane = threadIdx.x & 63, sub = lane >> 4, d16 = lane & 15;
    if (w >= 2 * BATCH) return;
    int node = (w < BATCH) ? users[w] : (NUM_USERS + items[w - BATCH]);
    int s0 = row_ptr[node], s1 = row_ptr[node + 1];
    const float4* b4 = (const float4*)bufB;
    float4 acc0 = {0.f, 0.f, 0.f, 0.f}, acc1 = {0.f, 0.f, 0.f, 0.f};
    int e = s0;
    for (; e + 8 <= s1; e += 8) {
        int i0 = ssrc[e + sub];
        int i1 = ssrc[e + 4 + sub];
        f4add(acc0, b4[(size_t)i0 * 16 + d16]);
        f4add(acc1, b4[(size_t)i1 * 16 + d16]);
    }
    int ee0 = e + sub;
    if (ee0 < s1) f4add(acc0, b4[(size_t)ssrc[ee0] * 16 + d16]);
    int ee1 = e + 4 + sub;
    if (ee1 < s1) f4add(acc1, b4[(size_t)ssrc[ee1] * 16 + d16]);
    f4add(acc0, acc1);
    acc0.x += __shfl_xor(acc0.x, 16, 64); acc0.x += __shfl_xor(acc0.x, 32, 64);
    acc0.y += __shfl_xor(acc0.y, 16, 64); acc0.y += __shfl_xor(acc0.y, 32, 64);
    acc0.z += __shfl_xor(acc0.z, 16, 64); acc0.z += __shfl_xor(acc0.z, 32, 64);
    acc0.w += __shfl_xor(acc0.w, 16, 64); acc0.w += __shfl_xor(acc0.w, 32, 64);
    if (sub == 0) {
        size_t ro = (size_t)node * 16 + d16;
        float4 ev = ((const float4*)emb)[ro];
        float4 av = ((const float4*)bufA)[ro];
        float4 bv = ((const float4*)bufB)[ro];
        float4 r;
        r.x = ev.x + av.x + bv.x + acc0.x;
        r.y = ev.y + av.y + bv.y + acc0.y;
        r.z = ev.z + av.z + bv.z + acc0.z;
        r.w = ev.w + av.w + bv.w + acc0.w;
        ((float4*)accs)[(size_t)w * 16 + d16] = r;
    }
}

__global__ void dot_out_k(const float* __restrict__ accs, float* __restrict__ out) {
    int t = (int)(blockIdx.x * blockDim.x + threadIdx.x);
    int b = t >> 6, lane = t & 63;
    if (b >= BATCH) return;
    float p = accs[(size_t)b * EDIM + lane] * accs[(size_t)(BATCH + b) * EDIM + lane];
    #pragma unroll
    for (int off = 32; off; off >>= 1) p += __shfl_down(p, off, 64);
    if (lane == 0) out[b] = p * (1.0f / 16.0f);
}

// ---------------- fallback (baseline atomic path) ----------------

__global__ void acc_batch_k(const float* __restrict__ cur, const int* __restrict__ users,
                            const int* __restrict__ items, float* __restrict__ accs, int first) {
    int t = (int)(blockIdx.x * blockDim.x + threadIdx.x);
    int row = t >> 6, lane = t & 63;
    if (row >= 2 * BATCH) return;
    int node = (row < BATCH) ? users[row] : (NUM_USERS + items[row - BATCH]);
    float v = cur[(size_t)node * EDIM + lane];
    size_t o = (size_t)row * EDIM + lane;
    if (first) accs[o] = v;
    else       accs[o] += v;
}

__global__ void scatter_add_k(const float* __restrict__ cur, float* __restrict__ nxt,
                              const int* __restrict__ src, const int* __restrict__ dst) {
    int w = (int)((blockIdx.x * blockDim.x + threadIdx.x) >> 6);
    int lane = threadIdx.x & 63;
    if (w >= NEDGES) return;
    float v = cur[(size_t)src[w] * EDIM + lane];
    atomicAdd(&nxt[(size_t)dst[w] * EDIM + lane], v);
}

extern "C" void kernel_launch(void* const* d_in, const int* in_sizes, int n_in,
                              void* d_out, int out_size, void* d_ws, size_t ws_size,
                              hipStream_t stream) {
    const float* emb   = (const float*)d_in[0];
    const int*   edge  = (const int*)d_in[1];
    const int*   src   = edge;            // edge_index[0]
    const int*   dst   = edge + NEDGES;   // edge_index[1]
    const int*   users = (const int*)d_in[2];
    const int*   items = (const int*)d_in[3];
    float*       out   = (float*)d_out;

    const size_t bufBytes = (size_t)NNODES * EDIM * sizeof(float); // 76.8 MB

    // workspace layout (zero-region is contiguous: one memset)
    size_t off = 0;
    float* bufA = (float*)((char*)d_ws + off); off = align256(off + bufBytes);
    float* bufB = (float*)((char*)d_ws + off); off = align256(off + bufBytes);
    float* accs = (float*)((char*)d_ws + off); off = align256(off + (size_t)2 * BATCH * EDIM * sizeof(float));
    int* row_ptr = (int*)((char*)d_ws + off); off = align256(off + (size_t)(NNODES + 1) * sizeof(int));
    int* ssrc    = (int*)((char*)d_ws + off); off = align256(off + (size_t)NEDGES * sizeof(int));
    unsigned char* need = (unsigned char*)((char*)d_ws + off); off = align256(off + (size_t)NNODES);
    const size_t zeroBase = off;
    int* counts    = (int*)((char*)d_ws + off); off += (size_t)NNODES * sizeof(int);
    int* cursor    = (int*)((char*)d_ws + off); off += (size_t)NNODES * sizeof(int);
    int* chunk_tot = (int*)((char*)d_ws + off); off += (size_t)NCHUNKS * sizeof(int);
    unsigned char* mS = (unsigned char*)((char*)d_ws + off); off += (size_t)NNODES;
    unsigned char* mA = (unsigned char*)((char*)d_ws + off); off += (size_t)NNODES;
    unsigned char* mB = (unsigned char*)((char*)d_ws + off); off += (size_t)NNODES;
    const size_t zeroBytes = off - zeroBase;
    const size_t needed = align256(off);

    const dim3 blk(256);
    const int edgeBlocks = (NEDGES + 255) / 256;
    const int nodeBlocks = (NNODES + 255) / 256;
    const int sampBlocks = (2 * BATCH * 64 + 255) / 256;
    const int dotBlocks  = (BATCH * 64 + 255) / 256;

    if (ws_size >= needed) {
        hipMemsetAsync((char*)d_ws + zeroBase, 0, zeroBytes, stream);
        mark_sampled_k<<<(2 * BATCH + 255) / 256, blk, 0, stream>>>(users, items, mS);
        histA_k<<<edgeBlocks, blk, 0, stream>>>(src, dst, counts, mS, mA);
        scan_chunk_k<<<NCHUNKS, blk, 0, stream>>>(counts, row_ptr, chunk_tot);
        scan_tops_k<<<1, 64, 0, stream>>>(chunk_tot, row_ptr);
        add_off_k<<<nodeBlocks, blk, 0, stream>>>(row_ptr, chunk_tot);
        fillB_k<<<edgeBlocks, blk, 0, stream>>>(src, dst, row_ptr, cursor, ssrc, mS, mA, mB);
        combine_k<<<nodeBlocks, blk, 0, stream>>>(mS, mA, mB, need);

        prop_f4_k<<<PROP_BLOCKS, blk, 0, stream>>>(emb,  bufA, row_ptr, ssrc, need, 1);  // layer 1
        prop_f4_k<<<PROP_BLOCKS, blk, 0, stream>>>(bufA, bufB, row_ptr, ssrc, need, 2);  // layer 2
        final_acc_k<<<sampBlocks, blk, 0, stream>>>(emb, bufA, bufB, users, items, row_ptr, ssrc, accs);
        dot_out_k<<<dotBlocks, blk, 0, stream>>>(accs, out);
    } else {
        // ---- fallback: baseline atomic path ----
        const int scatterBlocks = (NEDGES + 3) / 4;
        acc_batch_k<<<sampBlocks, blk, 0, stream>>>(emb, users, items, accs, 1);
        const float* cur = emb;
        float* bufs[2] = {bufA, bufB};
        for (int l = 0; l < 3; ++l) {
            float* nxt = bufs[l & 1];
            hipMemsetAsync(nxt, 0, bufBytes, stream);
            scatter_add_k<<<scatterBlocks, blk, 0, stream>>>(cur, nxt, src, dst);
            acc_batch_k<<<sampBlocks, blk, 0, stream>>>(nxt, users, items, accs, 0);
            cur = nxt;
        }
        dot_out_k<<<dotBlocks, blk, 0, stream>>>(accs, out);
    }
}

// Round 11
// 189.622 us; speedup vs baseline: 1.5088x; 1.0856x over previous
//
#include <hip/hip_runtime.h>

#define NUM_USERS 100000
#define NUM_ITEMS 200000
#define NNODES    300000   // NUM_USERS + NUM_ITEMS
#define EDIM      64
#define NEDGES    1200000
#define BATCH     4096
#define CHUNK     1024
#define NCHUNKS   ((NNODES + CHUNK - 1) / CHUNK)   // 293
#define NBLKN     ((NNODES + 255) / 256)           // 1172 node-blocks

static inline size_t align256(size_t x) { return (x + 255) & ~(size_t)255; }

__device__ __forceinline__ void f4add(float4& a, const float4& b) {
    a.x += b.x; a.y += b.y; a.z += b.z; a.w += b.w;
}

// ---------------- marking + CSR build (2 fused edge passes) ----------------

__global__ void mark_sampled_k(const int* __restrict__ users, const int* __restrict__ items,
                               unsigned char* __restrict__ mS) {
    int t = (int)(blockIdx.x * blockDim.x + threadIdx.x);
    if (t >= 2 * BATCH) return;
    int node = (t < BATCH) ? users[t] : (NUM_USERS + items[t - BATCH]);
    mS[node] = 1;
}

// Pass 1 over edges: histogram counts[dst] + markA (mA[src]=1 if dst sampled).
__global__ void histA_k(const int* __restrict__ src, const int* __restrict__ dst,
                        int* __restrict__ counts, const unsigned char* __restrict__ mS,
                        unsigned char* __restrict__ mA) {
    int e = (int)(blockIdx.x * blockDim.x + threadIdx.x);
    if (e >= NEDGES) return;
    int d = dst[e];
    atomicAdd(&counts[d], 1);
    if (mS[d]) mA[src[e]] = 1;
}

__global__ void scan_chunk_k(const int* __restrict__ counts, int* __restrict__ row_ptr,
                             int* __restrict__ chunk_tot) {
    __shared__ int sm[256];
    int t = threadIdx.x;
    int base = (int)blockIdx.x * CHUNK + t * 4;
    int v0 = (base + 0 < NNODES) ? counts[base + 0] : 0;
    int v1 = (base + 1 < NNODES) ? counts[base + 1] : 0;
    int v2 = (base + 2 < NNODES) ? counts[base + 2] : 0;
    int v3 = (base + 3 < NNODES) ? counts[base + 3] : 0;
    int ts = v0 + v1 + v2 + v3;
    sm[t] = ts;
    __syncthreads();
    for (int off = 1; off < 256; off <<= 1) {
        int x = (t >= off) ? sm[t - off] : 0;
        __syncthreads();
        sm[t] += x;
        __syncthreads();
    }
    int run = sm[t] - ts;
    if (t == 255) chunk_tot[blockIdx.x] = sm[255];
    if (base + 0 < NNODES) row_ptr[base + 0] = run; run += v0;
    if (base + 1 < NNODES) row_ptr[base + 1] = run; run += v1;
    if (base + 2 < NNODES) row_ptr[base + 2] = run; run += v2;
    if (base + 3 < NNODES) row_ptr[base + 3] = run;
}

// 64-lane shfl scan of the 293 chunk totals (exclusive, in-place).
__global__ void scan_tops_k(int* __restrict__ chunk_tot, int* __restrict__ row_ptr) {
    int lane = threadIdx.x & 63;
    int carry = 0;
    for (int base = 0; base < NCHUNKS; base += 64) {
        int idx = base + lane;
        int v = (idx < NCHUNKS) ? chunk_tot[idx] : 0;
        int x = v;
        #pragma unroll
        for (int off = 1; off < 64; off <<= 1) {
            int t = __shfl_up(x, off, 64);
            if (lane >= off) x += t;
        }
        if (idx < NCHUNKS) chunk_tot[idx] = carry + x - v;   // exclusive
        carry += __shfl(x, 63, 64);
    }
    if (lane == 0) row_ptr[NNODES] = carry;
}

__global__ void add_off_k(int* __restrict__ row_ptr, const int* __restrict__ chunk_tot) {
    int i = (int)(blockIdx.x * blockDim.x + threadIdx.x);
    if (i < NNODES) row_ptr[i] += chunk_tot[i / CHUNK];
}

// Pass 2 over edges: CSR fill + markB (mB[src]=1 if dst in mS|mA).
__global__ void fillB_k(const int* __restrict__ src, const int* __restrict__ dst,
                        const int* __restrict__ row_ptr, int* __restrict__ cursor,
                        int* __restrict__ ssrc, const unsigned char* __restrict__ mS,
                        const unsigned char* __restrict__ mA, unsigned char* __restrict__ mB) {
    int e = (int)(blockIdx.x * blockDim.x + threadIdx.x);
    if (e >= NEDGES) return;
    int d = dst[e];
    int s = src[e];
    int pos = atomicAdd(&cursor[d], 1);
    ssrc[row_ptr[d] + pos] = s;
    if (mS[d] | mA[d]) mB[s] = 1;
}

// ---- scan-based worklist compaction: NO shared counters (r8/r9 lesson:
// single-counter device atomics serialize ~11.6ns each regardless of
// wave-aggregation). count -> 64-lane scan -> re-ballot emit. wl sorted. ----

__global__ void count_wl_k(const unsigned char* __restrict__ mS, const unsigned char* __restrict__ mA,
                           const unsigned char* __restrict__ mB, int* __restrict__ cnt1,
                           int* __restrict__ cnt2) {
    __shared__ int w1[4], w2[4];
    int i = (int)(blockIdx.x * blockDim.x + threadIdx.x);
    int lane = threadIdx.x & 63, wv = threadIdx.x >> 6;
    unsigned char s = 0, a = 0, b = 0;
    if (i < NNODES) { s = mS[i]; a = mA[i]; b = mB[i]; }
    bool p1 = (i < NNODES) && (s | a | b);
    bool p2 = (i < NNODES) && (s | a);
    unsigned long long b1 = __ballot(p1), b2 = __ballot(p2);
    if (lane == 0) { w1[wv] = __popcll(b1); w2[wv] = __popcll(b2); }
    __syncthreads();
    if (threadIdx.x == 0) {
        cnt1[blockIdx.x] = w1[0] + w1[1] + w1[2] + w1[3];
        cnt2[blockIdx.x] = w2[0] + w2[1] + w2[2] + w2[3];
    }
}

__global__ void scan_blocks_k(int* __restrict__ cnt1, int* __restrict__ cnt2, int* __restrict__ wl_n) {
    int lane = threadIdx.x & 63;
    int carry1 = 0, carry2 = 0;
    for (int base = 0; base < NBLKN; base += 64) {
        int idx = base + lane;
        int v1 = (idx < NBLKN) ? cnt1[idx] : 0;
        int v2 = (idx < NBLKN) ? cnt2[idx] : 0;
        int x1 = v1, x2 = v2;
        #pragma unroll
        for (int off = 1; off < 64; off <<= 1) {
            int t1 = __shfl_up(x1, off, 64);
            int t2 = __shfl_up(x2, off, 64);
            if (lane >= off) { x1 += t1; x2 += t2; }
        }
        if (idx < NBLKN) { cnt1[idx] = carry1 + x1 - v1; cnt2[idx] = carry2 + x2 - v2; }
        carry1 += __shfl(x1, 63, 64);
        carry2 += __shfl(x2, 63, 64);
    }
    if (lane == 0) { wl_n[0] = carry1; wl_n[1] = carry2; }
}

__global__ void emit_wl_k(const unsigned char* __restrict__ mS, const unsigned char* __restrict__ mA,
                          const unsigned char* __restrict__ mB, const int* __restrict__ cnt1,
                          const int* __restrict__ cnt2, int* __restrict__ wl1, int* __restrict__ wl2) {
    __shared__ int w1[4], w2[4];
    int i = (int)(blockIdx.x * blockDim.x + threadIdx.x);
    int lane = threadIdx.x & 63, wv = threadIdx.x >> 6;
    unsigned char s = 0, a = 0, b = 0;
    if (i < NNODES) { s = mS[i]; a = mA[i]; b = mB[i]; }
    bool p1 = (i < NNODES) && (s | a | b);
    bool p2 = (i < NNODES) && (s | a);
    unsigned long long b1 = __ballot(p1), b2 = __ballot(p2);
    if (lane == 0) { w1[wv] = __popcll(b1); w2[wv] = __popcll(b2); }
    __syncthreads();
    int off1 = 0, off2 = 0;
    for (int k = 0; k < wv; ++k) { off1 += w1[k]; off2 += w2[k]; }
    unsigned long long lt = (1ULL << lane) - 1;
    if (p1) wl1[cnt1[blockIdx.x] + off1 + __popcll(b1 & lt)] = i;
    if (p2) wl2[cnt2[blockIdx.x] + off2 + __popcll(b2 & lt)] = i;
}

// ---------------- propagation: worklist + manual prefetch pipeline ----------------

#define PROP_BLOCKS 2048   // 8192 waves

__global__ __launch_bounds__(256) void prop_f4_k(
        const float* __restrict__ cur, float* __restrict__ nxt,
        const int* __restrict__ row_ptr, const int* __restrict__ ssrc,
        const int* __restrict__ wl, const int* __restrict__ n_ptr) {
    int lane = threadIdx.x & 63;
    int sub = lane >> 4, d16 = lane & 15;
    int gw = (int)((blockIdx.x * blockDim.x + threadIdx.x) >> 6);
    int nw = (int)((gridDim.x * blockDim.x) >> 6);
    int n = *n_ptr;
    const float4* cur4 = (const float4*)cur;

    int i = gw;
    if (i >= n) return;
    int node = wl[i];
    int s0 = row_ptr[node];
    int s1 = row_ptr[node + 1];
    int ia = (s0 + sub     < s1) ? ssrc[s0 + sub]     : -1;
    int ib = (s0 + 4 + sub < s1) ? ssrc[s0 + 4 + sub] : -1;

    while (true) {
        // prefetch next iteration's descriptors (hides under current gathers)
        int j = i + nw;
        bool have_next = (j < n);
        int nnode = 0, ns0 = 0, ns1 = 0, nia = -1, nib = -1;
        if (have_next) {
            nnode = wl[j];
            ns0 = row_ptr[nnode];
            ns1 = row_ptr[nnode + 1];
            nia = (ns0 + sub     < ns1) ? ssrc[ns0 + sub]     : -1;
            nib = (ns0 + 4 + sub < ns1) ? ssrc[ns0 + 4 + sub] : -1;
        }
        // gather current node (first 8 edges via prefetched indices)
        float4 acc0 = {0.f, 0.f, 0.f, 0.f}, acc1 = {0.f, 0.f, 0.f, 0.f};
        if (ia >= 0) f4add(acc0, cur4[(size_t)ia * 16 + d16]);
        if (ib >= 0) f4add(acc1, cur4[(size_t)ib * 16 + d16]);
        for (int e = s0 + 8; e < s1; e += 8) {    // rare: deg > 8
            int p = e + sub, q = e + 4 + sub;
            if (p < s1) f4add(acc0, cur4[(size_t)ssrc[p] * 16 + d16]);
            if (q < s1) f4add(acc1, cur4[(size_t)ssrc[q] * 16 + d16]);
        }
        f4add(acc0, acc1);
        acc0.x += __shfl_xor(acc0.x, 16, 64); acc0.x += __shfl_xor(acc0.x, 32, 64);
        acc0.y += __shfl_xor(acc0.y, 16, 64); acc0.y += __shfl_xor(acc0.y, 32, 64);
        acc0.z += __shfl_xor(acc0.z, 16, 64); acc0.z += __shfl_xor(acc0.z, 32, 64);
        acc0.w += __shfl_xor(acc0.w, 16, 64); acc0.w += __shfl_xor(acc0.w, 32, 64);
        if (sub == 0) ((float4*)nxt)[(size_t)node * 16 + d16] = acc0;
        if (!have_next) break;
        i = j; node = nnode; s0 = ns0; s1 = ns1; ia = nia; ib = nib;
    }
}

// ---------------- fused layer-3 + layer-sum + dot (one wave per batch pair) ----------------

__device__ __forceinline__ float4 gather_row_sum(const float4* __restrict__ b4,
                                                 const int* __restrict__ ssrc,
                                                 int s0, int s1, int sub, int d16) {
    float4 acc0 = {0.f, 0.f, 0.f, 0.f}, acc1 = {0.f, 0.f, 0.f, 0.f};
    for (int e = s0; e < s1; e += 8) {
        int p = e + sub, q = e + 4 + sub;
        if (p < s1) f4add(acc0, b4[(size_t)ssrc[p] * 16 + d16]);
        if (q < s1) f4add(acc1, b4[(size_t)ssrc[q] * 16 + d16]);
    }
    f4add(acc0, acc1);
    return acc0;
}

__global__ __launch_bounds__(256) void final_dot_k(
        const float* __restrict__ emb, const float* __restrict__ bufA,
        const float* __restrict__ bufB, const int* __restrict__ users,
        const int* __restrict__ items, const int* __restrict__ row_ptr,
        const int* __restrict__ ssrc, float* __restrict__ out) {
    int t = (int)(blockIdx.x * blockDim.x + threadIdx.x);
    int b = t >> 6;
    if (b >= BATCH) return;
    int lane = threadIdx.x & 63, sub = lane >> 4, d16 = lane & 15;
    int nu = users[b], ni = NUM_USERS + items[b];
    int u0 = row_ptr[nu], u1 = row_ptr[nu + 1];
    int i0 = row_ptr[ni], i1 = row_ptr[ni + 1];
    const float4* b4 = (const float4*)bufB;
    float4 au = gather_row_sum(b4, ssrc, u0, u1, sub, d16);   // layer-3 @ user
    float4 ai = gather_row_sum(b4, ssrc, i0, i1, sub, d16);   // layer-3 @ item
    au.x += __shfl_xor(au.x, 16, 64); au.x += __shfl_xor(au.x, 32, 64);
    au.y += __shfl_xor(au.y, 16, 64); au.y += __shfl_xor(au.y, 32, 64);
    au.z += __shfl_xor(au.z, 16, 64); au.z += __shfl_xor(au.z, 32, 64);
    au.w += __shfl_xor(au.w, 16, 64); au.w += __shfl_xor(au.w, 32, 64);
    ai.x += __shfl_xor(ai.x, 16, 64); ai.x += __shfl_xor(ai.x, 32, 64);
    ai.y += __shfl_xor(ai.y, 16, 64); ai.y += __shfl_xor(ai.y, 32, 64);
    ai.z += __shfl_xor(ai.z, 16, 64); ai.z += __shfl_xor(ai.z, 32, 64);
    ai.w += __shfl_xor(ai.w, 16, 64); ai.w += __shfl_xor(ai.w, 32, 64);
    if (sub == 0) {
        size_t ru = (size_t)nu * 16 + d16, ri = (size_t)ni * 16 + d16;
        float4 eu = ((const float4*)emb)[ru], pu = ((const float4*)bufA)[ru], qu = ((const float4*)bufB)[ru];
        float4 ei = ((const float4*)emb)[ri], pi = ((const float4*)bufA)[ri], qi = ((const float4*)bufB)[ri];
        float fx = (eu.x + pu.x + qu.x + au.x) * (ei.x + pi.x + qi.x + ai.x);
        float fy = (eu.y + pu.y + qu.y + au.y) * (ei.y + pi.y + qi.y + ai.y);
        float fz = (eu.z + pu.z + qu.z + au.z) * (ei.z + pi.z + qi.z + ai.z);
        float fw = (eu.w + pu.w + qu.w + au.w) * (ei.w + pi.w + qi.w + ai.w);
        float p = fx + fy + fz + fw;
        p += __shfl_xor(p, 1, 64); p += __shfl_xor(p, 2, 64);
        p += __shfl_xor(p, 4, 64); p += __shfl_xor(p, 8, 64);
        if (d16 == 0) out[b] = p * (1.0f / 16.0f);
    }
}

// ---------------- fallback (baseline atomic path) ----------------

__global__ void acc_batch_k(const float* __restrict__ cur, const int* __restrict__ users,
                            const int* __restrict__ items, float* __restrict__ accs, int first) {
    int t = (int)(blockIdx.x * blockDim.x + threadIdx.x);
    int row = t >> 6, lane = t & 63;
    if (row >= 2 * BATCH) return;
    int node = (row < BATCH) ? users[row] : (NUM_USERS + items[row - BATCH]);
    float v = cur[(size_t)node * EDIM + lane];
    size_t o = (size_t)row * EDIM + lane;
    if (first) accs[o] = v;
    else       accs[o] += v;
}

__global__ void scatter_add_k(const float* __restrict__ cur, float* __restrict__ nxt,
                              const int* __restrict__ src, const int* __restrict__ dst) {
    int w = (int)((blockIdx.x * blockDim.x + threadIdx.x) >> 6);
    int lane = threadIdx.x & 63;
    if (w >= NEDGES) return;
    float v = cur[(size_t)src[w] * EDIM + lane];
    atomicAdd(&nxt[(size_t)dst[w] * EDIM + lane], v);
}

__global__ void dot_out_k(const float* __restrict__ accs, float* __restrict__ out) {
    int t = (int)(blockIdx.x * blockDim.x + threadIdx.x);
    int b = t >> 6, lane = t & 63;
    if (b >= BATCH) return;
    float p = accs[(size_t)b * EDIM + lane] * accs[(size_t)(BATCH + b) * EDIM + lane];
    #pragma unroll
    for (int off = 32; off; off >>= 1) p += __shfl_down(p, off, 64);
    if (lane == 0) out[b] = p * (1.0f / 16.0f);
}

extern "C" void kernel_launch(void* const* d_in, const int* in_sizes, int n_in,
                              void* d_out, int out_size, void* d_ws, size_t ws_size,
                              hipStream_t stream) {
    const float* emb   = (const float*)d_in[0];
    const int*   edge  = (const int*)d_in[1];
    const int*   src   = edge;            // edge_index[0]
    const int*   dst   = edge + NEDGES;   // edge_index[1]
    const int*   users = (const int*)d_in[2];
    const int*   items = (const int*)d_in[3];
    float*       out   = (float*)d_out;

    const size_t bufBytes = (size_t)NNODES * EDIM * sizeof(float); // 76.8 MB

    // workspace layout (zero-region is contiguous: one memset)
    size_t off = 0;
    float* bufA = (float*)((char*)d_ws + off); off = align256(off + bufBytes);
    float* bufB = (float*)((char*)d_ws + off); off = align256(off + bufBytes);
    float* accs = (float*)((char*)d_ws + off); off = align256(off + (size_t)2 * BATCH * EDIM * sizeof(float));
    int* row_ptr = (int*)((char*)d_ws + off); off = align256(off + (size_t)(NNODES + 1) * sizeof(int));
    int* ssrc    = (int*)((char*)d_ws + off); off = align256(off + (size_t)NEDGES * sizeof(int));
    int* wl1     = (int*)((char*)d_ws + off); off = align256(off + (size_t)NNODES * sizeof(int));
    int* wl2     = (int*)((char*)d_ws + off); off = align256(off + (size_t)NNODES * sizeof(int));
    int* cnt1    = (int*)((char*)d_ws + off); off = align256(off + (size_t)NBLKN * sizeof(int));
    int* cnt2    = (int*)((char*)d_ws + off); off = align256(off + (size_t)NBLKN * sizeof(int));
    int* wl_n    = (int*)((char*)d_ws + off); off = align256(off + 2 * sizeof(int));
    int* chunk_tot = (int*)((char*)d_ws + off); off = align256(off + (size_t)NCHUNKS * sizeof(int));
    const size_t zeroBase = off;
    int* counts    = (int*)((char*)d_ws + off); off += (size_t)NNODES * sizeof(int);
    int* cursor    = (int*)((char*)d_ws + off); off += (size_t)NNODES * sizeof(int);
    unsigned char* mS = (unsigned char*)((char*)d_ws + off); off += (size_t)NNODES;
    unsigned char* mA = (unsigned char*)((char*)d_ws + off); off += (size_t)NNODES;
    unsigned char* mB = (unsigned char*)((char*)d_ws + off); off += (size_t)NNODES;
    const size_t zeroBytes = off - zeroBase;
    const size_t needed = align256(off);

    const dim3 blk(256);
    const int edgeBlocks = (NEDGES + 255) / 256;
    const int nodeBlocks = NBLKN;
    const int sampBlocks = (2 * BATCH * 64 + 255) / 256;
    const int dotBlocks  = (BATCH * 64 + 255) / 256;

    if (ws_size >= needed) {
        hipMemsetAsync((char*)d_ws + zeroBase, 0, zeroBytes, stream);
        mark_sampled_k<<<(2 * BATCH + 255) / 256, blk, 0, stream>>>(users, items, mS);
        histA_k<<<edgeBlocks, blk, 0, stream>>>(src, dst, counts, mS, mA);
        scan_chunk_k<<<NCHUNKS, blk, 0, stream>>>(counts, row_ptr, chunk_tot);
        scan_tops_k<<<1, 64, 0, stream>>>(chunk_tot, row_ptr);
        add_off_k<<<nodeBlocks, blk, 0, stream>>>(row_ptr, chunk_tot);
        fillB_k<<<edgeBlocks, blk, 0, stream>>>(src, dst, row_ptr, cursor, ssrc, mS, mA, mB);
        count_wl_k<<<nodeBlocks, blk, 0, stream>>>(mS, mA, mB, cnt1, cnt2);
        scan_blocks_k<<<1, 64, 0, stream>>>(cnt1, cnt2, wl_n);
        emit_wl_k<<<nodeBlocks, blk, 0, stream>>>(mS, mA, mB, cnt1, cnt2, wl1, wl2);

        prop_f4_k<<<PROP_BLOCKS, blk, 0, stream>>>(emb,  bufA, row_ptr, ssrc, wl1, wl_n);      // layer 1
        prop_f4_k<<<PROP_BLOCKS, blk, 0, stream>>>(bufA, bufB, row_ptr, ssrc, wl2, wl_n + 1);  // layer 2
        final_dot_k<<<dotBlocks, blk, 0, stream>>>(emb, bufA, bufB, users, items, row_ptr, ssrc, out);
    } else {
        // ---- fallback: baseline atomic path ----
        const int scatterBlocks = (NEDGES + 3) / 4;
        acc_batch_k<<<sampBlocks, blk, 0, stream>>>(emb, users, items, accs, 1);
        const float* cur = emb;
        float* bufs[2] = {bufA, bufB};
        for (int l = 0; l < 3; ++l) {
            float* nxt = bufs[l & 1];
            hipMemsetAsync(nxt, 0, bufBytes, stream);
            scatter_add_k<<<scatterBlocks, blk, 0, stream>>>(cur, nxt, src, dst);
            acc_batch_k<<<sampBlocks, blk, 0, stream>>>(nxt, users, items, accs, 0);
            cur = nxt;
        }
        dot_out_k<<<dotBlocks, blk, 0, stream>>>(accs, out);
    }
}

// Round 12
// 164.653 us; speedup vs baseline: 1.7377x; 1.1516x over previous
//
#include <hip/hip_runtime.h>

#define NUM_USERS 100000
#define NUM_ITEMS 200000
#define NNODES    300000   // NUM_USERS + NUM_ITEMS
#define EDIM      64
#define NEDGES    1200000
#define BATCH     4096
#define CHUNK     1024
#define NCHUNKS   ((NNODES + CHUNK - 1) / CHUNK)   // 293
#define NBLKN     ((NNODES + 255) / 256)           // 1172 node-blocks

static inline size_t align256(size_t x) { return (x + 255) & ~(size_t)255; }

__device__ __forceinline__ void f4add(float4& a, const float4& b) {
    a.x += b.x; a.y += b.y; a.z += b.z; a.w += b.w;
}

// ---------------- marking + CSR build ----------------

__global__ void mark_sampled_k(const int* __restrict__ users, const int* __restrict__ items,
                               unsigned char* __restrict__ mS) {
    int t = (int)(blockIdx.x * blockDim.x + threadIdx.x);
    if (t >= 2 * BATCH) return;
    int node = (t < BATCH) ? users[t] : (NUM_USERS + items[t - BATCH]);
    mS[node] = 1;
}

// Pass 1 over edges: histogram counts[dst] (KEEP the returned rank as epos[e])
// + markA (mA[src]=1 if dst sampled).
__global__ void hist_epos_k(const int* __restrict__ src, const int* __restrict__ dst,
                            int* __restrict__ counts, int* __restrict__ epos,
                            const unsigned char* __restrict__ mS, unsigned char* __restrict__ mA) {
    int e = (int)(blockIdx.x * blockDim.x + threadIdx.x);
    if (e >= NEDGES) return;
    int d = dst[e];
    epos[e] = atomicAdd(&counts[d], 1);
    if (mS[d]) mA[src[e]] = 1;
}

__global__ void scan_chunk_k(const int* __restrict__ counts, int* __restrict__ row_ptr,
                             int* __restrict__ chunk_tot) {
    __shared__ int sm[256];
    int t = threadIdx.x;
    int base = (int)blockIdx.x * CHUNK + t * 4;
    int v0 = (base + 0 < NNODES) ? counts[base + 0] : 0;
    int v1 = (base + 1 < NNODES) ? counts[base + 1] : 0;
    int v2 = (base + 2 < NNODES) ? counts[base + 2] : 0;
    int v3 = (base + 3 < NNODES) ? counts[base + 3] : 0;
    int ts = v0 + v1 + v2 + v3;
    sm[t] = ts;
    __syncthreads();
    for (int off = 1; off < 256; off <<= 1) {
        int x = (t >= off) ? sm[t - off] : 0;
        __syncthreads();
        sm[t] += x;
        __syncthreads();
    }
    int run = sm[t] - ts;
    if (t == 255) chunk_tot[blockIdx.x] = sm[255];
    if (base + 0 < NNODES) row_ptr[base + 0] = run; run += v0;
    if (base + 1 < NNODES) row_ptr[base + 1] = run; run += v1;
    if (base + 2 < NNODES) row_ptr[base + 2] = run; run += v2;
    if (base + 3 < NNODES) row_ptr[base + 3] = run;
}

// 64-lane shfl scan of the 293 chunk totals (exclusive, in-place).
__global__ void scan_tops_k(int* __restrict__ chunk_tot, int* __restrict__ row_ptr) {
    int lane = threadIdx.x & 63;
    int carry = 0;
    for (int base = 0; base < NCHUNKS; base += 64) {
        int idx = base + lane;
        int v = (idx < NCHUNKS) ? chunk_tot[idx] : 0;
        int x = v;
        #pragma unroll
        for (int off = 1; off < 64; off <<= 1) {
            int t = __shfl_up(x, off, 64);
            if (lane >= off) x += t;
        }
        if (idx < NCHUNKS) chunk_tot[idx] = carry + x - v;   // exclusive
        carry += __shfl(x, 63, 64);
    }
    if (lane == 0) row_ptr[NNODES] = carry;
}

__global__ void add_off_k(int* __restrict__ row_ptr, const int* __restrict__ chunk_tot) {
    int i = (int)(blockIdx.x * blockDim.x + threadIdx.x);
    if (i < NNODES) row_ptr[i] += chunk_tot[i / CHUNK];
}

// Pass 2 over edges: pure scatter (NO atomics in the chain — position comes
// from epos) + markB (mB[src]=1 if dst in mS|mA).
__global__ void scatter_fill_k(const int* __restrict__ src, const int* __restrict__ dst,
                               const int* __restrict__ row_ptr, const int* __restrict__ epos,
                               int* __restrict__ ssrc, const unsigned char* __restrict__ mS,
                               const unsigned char* __restrict__ mA, unsigned char* __restrict__ mB) {
    int e = (int)(blockIdx.x * blockDim.x + threadIdx.x);
    if (e >= NEDGES) return;
    int d = dst[e];
    int s = src[e];
    ssrc[row_ptr[d] + epos[e]] = s;
    if (mS[d] | mA[d]) mB[s] = 1;
}

// ---- scan-based worklist compaction (no shared counters; r8/r9 lesson) ----

__global__ void count_wl_k(const unsigned char* __restrict__ mS, const unsigned char* __restrict__ mA,
                           const unsigned char* __restrict__ mB, int* __restrict__ cnt1,
                           int* __restrict__ cnt2) {
    __shared__ int w1[4], w2[4];
    int i = (int)(blockIdx.x * blockDim.x + threadIdx.x);
    int lane = threadIdx.x & 63, wv = threadIdx.x >> 6;
    unsigned char s = 0, a = 0, b = 0;
    if (i < NNODES) { s = mS[i]; a = mA[i]; b = mB[i]; }
    bool p1 = (i < NNODES) && (s | a | b);
    bool p2 = (i < NNODES) && (s | a);
    unsigned long long b1 = __ballot(p1), b2 = __ballot(p2);
    if (lane == 0) { w1[wv] = __popcll(b1); w2[wv] = __popcll(b2); }
    __syncthreads();
    if (threadIdx.x == 0) {
        cnt1[blockIdx.x] = w1[0] + w1[1] + w1[2] + w1[3];
        cnt2[blockIdx.x] = w2[0] + w2[1] + w2[2] + w2[3];
    }
}

__global__ void scan_blocks_k(int* __restrict__ cnt1, int* __restrict__ cnt2, int* __restrict__ wl_n) {
    int lane = threadIdx.x & 63;
    int carry1 = 0, carry2 = 0;
    for (int base = 0; base < NBLKN; base += 64) {
        int idx = base + lane;
        int v1 = (idx < NBLKN) ? cnt1[idx] : 0;
        int v2 = (idx < NBLKN) ? cnt2[idx] : 0;
        int x1 = v1, x2 = v2;
        #pragma unroll
        for (int off = 1; off < 64; off <<= 1) {
            int t1 = __shfl_up(x1, off, 64);
            int t2 = __shfl_up(x2, off, 64);
            if (lane >= off) { x1 += t1; x2 += t2; }
        }
        if (idx < NBLKN) { cnt1[idx] = carry1 + x1 - v1; cnt2[idx] = carry2 + x2 - v2; }
        carry1 += __shfl(x1, 63, 64);
        carry2 += __shfl(x2, 63, 64);
    }
    if (lane == 0) { wl_n[0] = carry1; wl_n[1] = carry2; }
}

__global__ void emit_wl_k(const unsigned char* __restrict__ mS, const unsigned char* __restrict__ mA,
                          const unsigned char* __restrict__ mB, const int* __restrict__ cnt1,
                          const int* __restrict__ cnt2, int* __restrict__ wl1, int* __restrict__ wl2) {
    __shared__ int w1[4], w2[4];
    int i = (int)(blockIdx.x * blockDim.x + threadIdx.x);
    int lane = threadIdx.x & 63, wv = threadIdx.x >> 6;
    unsigned char s = 0, a = 0, b = 0;
    if (i < NNODES) { s = mS[i]; a = mA[i]; b = mB[i]; }
    bool p1 = (i < NNODES) && (s | a | b);
    bool p2 = (i < NNODES) && (s | a);
    unsigned long long b1 = __ballot(p1), b2 = __ballot(p2);
    if (lane == 0) { w1[wv] = __popcll(b1); w2[wv] = __popcll(b2); }
    __syncthreads();
    int off1 = 0, off2 = 0;
    for (int k = 0; k < wv; ++k) { off1 += w1[k]; off2 += w2[k]; }
    unsigned long long lt = (1ULL << lane) - 1;
    if (p1) wl1[cnt1[blockIdx.x] + off1 + __popcll(b1 & lt)] = i;
    if (p2) wl2[cnt2[blockIdx.x] + off2 + __popcll(b2 & lt)] = i;
}

// ---------------- propagation: worklist + manual prefetch pipeline ----------------

#define PROP_BLOCKS 2048   // 8192 waves

__global__ __launch_bounds__(256) void prop_f4_k(
        const float* __restrict__ cur, float* __restrict__ nxt,
        const int* __restrict__ row_ptr, const int* __restrict__ ssrc,
        const int* __restrict__ wl, const int* __restrict__ n_ptr) {
    int lane = threadIdx.x & 63;
    int sub = lane >> 4, d16 = lane & 15;
    int gw = (int)((blockIdx.x * blockDim.x + threadIdx.x) >> 6);
    int nw = (int)((gridDim.x * blockDim.x) >> 6);
    int n = *n_ptr;
    const float4* cur4 = (const float4*)cur;

    int i = gw;
    if (i >= n) return;
    int node = wl[i];
    int s0 = row_ptr[node];
    int s1 = row_ptr[node + 1];
    int ia = (s0 + sub     < s1) ? ssrc[s0 + sub]     : -1;
    int ib = (s0 + 4 + sub < s1) ? ssrc[s0 + 4 + sub] : -1;

    while (true) {
        // prefetch next iteration's descriptors (hides under current gathers)
        int j = i + nw;
        bool have_next = (j < n);
        int nnode = 0, ns0 = 0, ns1 = 0, nia = -1, nib = -1;
        if (have_next) {
            nnode = wl[j];
            ns0 = row_ptr[nnode];
            ns1 = row_ptr[nnode + 1];
            nia = (ns0 + sub     < ns1) ? ssrc[ns0 + sub]     : -1;
            nib = (ns0 + 4 + sub < ns1) ? ssrc[ns0 + 4 + sub] : -1;
        }
        // gather current node (first 8 edges via prefetched indices)
        float4 acc0 = {0.f, 0.f, 0.f, 0.f}, acc1 = {0.f, 0.f, 0.f, 0.f};
        if (ia >= 0) f4add(acc0, cur4[(size_t)ia * 16 + d16]);
        if (ib >= 0) f4add(acc1, cur4[(size_t)ib * 16 + d16]);
        for (int e = s0 + 8; e < s1; e += 8) {    // rare: deg > 8
            int p = e + sub, q = e + 4 + sub;
            if (p < s1) f4add(acc0, cur4[(size_t)ssrc[p] * 16 + d16]);
            if (q < s1) f4add(acc1, cur4[(size_t)ssrc[q] * 16 + d16]);
        }
        f4add(acc0, acc1);
        acc0.x += __shfl_xor(acc0.x, 16, 64); acc0.x += __shfl_xor(acc0.x, 32, 64);
        acc0.y += __shfl_xor(acc0.y, 16, 64); acc0.y += __shfl_xor(acc0.y, 32, 64);
        acc0.z += __shfl_xor(acc0.z, 16, 64); acc0.z += __shfl_xor(acc0.z, 32, 64);
        acc0.w += __shfl_xor(acc0.w, 16, 64); acc0.w += __shfl_xor(acc0.w, 32, 64);
        if (sub == 0) ((float4*)nxt)[(size_t)node * 16 + d16] = acc0;
        if (!have_next) break;
        i = j; node = nnode; s0 = ns0; s1 = ns1; ia = nia; ib = nib;
    }
}

// ---------------- fused layer-3 + layer-sum + dot (one wave per batch pair) ----------------

__device__ __forceinline__ float4 gather_row_sum(const float4* __restrict__ b4,
                                                 const int* __restrict__ ssrc,
                                                 int s0, int s1, int sub, int d16) {
    float4 acc0 = {0.f, 0.f, 0.f, 0.f}, acc1 = {0.f, 0.f, 0.f, 0.f};
    for (int e = s0; e < s1; e += 8) {
        int p = e + sub, q = e + 4 + sub;
        if (p < s1) f4add(acc0, b4[(size_t)ssrc[p] * 16 + d16]);
        if (q < s1) f4add(acc1, b4[(size_t)ssrc[q] * 16 + d16]);
    }
    f4add(acc0, acc1);
    return acc0;
}

__global__ __launch_bounds__(256) void final_dot_k(
        const float* __restrict__ emb, const float* __restrict__ bufA,
        const float* __restrict__ bufB, const int* __restrict__ users,
        const int* __restrict__ items, const int* __restrict__ row_ptr,
        const int* __restrict__ ssrc, float* __restrict__ out) {
    int t = (int)(blockIdx.x * blockDim.x + threadIdx.x);
    int b = t >> 6;
    if (b >= BATCH) return;
    int lane = threadIdx.x & 63, sub = lane >> 4, d16 = lane & 15;
    int nu = users[b], ni = NUM_USERS + items[b];
    int u0 = row_ptr[nu], u1 = row_ptr[nu + 1];
    int i0 = row_ptr[ni], i1 = row_ptr[ni + 1];
    const float4* b4 = (const float4*)bufB;
    float4 au = gather_row_sum(b4, ssrc, u0, u1, sub, d16);   // layer-3 @ user
    float4 ai = gather_row_sum(b4, ssrc, i0, i1, sub, d16);   // layer-3 @ item
    au.x += __shfl_xor(au.x, 16, 64); au.x += __shfl_xor(au.x, 32, 64);
    au.y += __shfl_xor(au.y, 16, 64); au.y += __shfl_xor(au.y, 32, 64);
    au.z += __shfl_xor(au.z, 16, 64); au.z += __shfl_xor(au.z, 32, 64);
    au.w += __shfl_xor(au.w, 16, 64); au.w += __shfl_xor(au.w, 32, 64);
    ai.x += __shfl_xor(ai.x, 16, 64); ai.x += __shfl_xor(ai.x, 32, 64);
    ai.y += __shfl_xor(ai.y, 16, 64); ai.y += __shfl_xor(ai.y, 32, 64);
    ai.z += __shfl_xor(ai.z, 16, 64); ai.z += __shfl_xor(ai.z, 32, 64);
    ai.w += __shfl_xor(ai.w, 16, 64); ai.w += __shfl_xor(ai.w, 32, 64);
    if (sub == 0) {
        size_t ru = (size_t)nu * 16 + d16, ri = (size_t)ni * 16 + d16;
        float4 eu = ((const float4*)emb)[ru], pu = ((const float4*)bufA)[ru], qu = ((const float4*)bufB)[ru];
        float4 ei = ((const float4*)emb)[ri], pi = ((const float4*)bufA)[ri], qi = ((const float4*)bufB)[ri];
        float fx = (eu.x + pu.x + qu.x + au.x) * (ei.x + pi.x + qi.x + ai.x);
        float fy = (eu.y + pu.y + qu.y + au.y) * (ei.y + pi.y + qi.y + ai.y);
        float fz = (eu.z + pu.z + qu.z + au.z) * (ei.z + pi.z + qi.z + ai.z);
        float fw = (eu.w + pu.w + qu.w + au.w) * (ei.w + pi.w + qi.w + ai.w);
        float p = fx + fy + fz + fw;
        p += __shfl_xor(p, 1, 64); p += __shfl_xor(p, 2, 64);
        p += __shfl_xor(p, 4, 64); p += __shfl_xor(p, 8, 64);
        if (d16 == 0) out[b] = p * (1.0f / 16.0f);
    }
}

// ---------------- fallback (baseline atomic path) ----------------

__global__ void acc_batch_k(const float* __restrict__ cur, const int* __restrict__ users,
                            const int* __restrict__ items, float* __restrict__ accs, int first) {
    int t = (int)(blockIdx.x * blockDim.x + threadIdx.x);
    int row = t >> 6, lane = t & 63;
    if (row >= 2 * BATCH) return;
    int node = (row < BATCH) ? users[row] : (NUM_USERS + items[row - BATCH]);
    float v = cur[(size_t)node * EDIM + lane];
    size_t o = (size_t)row * EDIM + lane;
    if (first) accs[o] = v;
    else       accs[o] += v;
}

__global__ void scatter_add_k(const float* __restrict__ cur, float* __restrict__ nxt,
                              const int* __restrict__ src, const int* __restrict__ dst) {
    int w = (int)((blockIdx.x * blockDim.x + threadIdx.x) >> 6);
    int lane = threadIdx.x & 63;
    if (w >= NEDGES) return;
    float v = cur[(size_t)src[w] * EDIM + lane];
    atomicAdd(&nxt[(size_t)dst[w] * EDIM + lane], v);
}

__global__ void dot_out_k(const float* __restrict__ accs, float* __restrict__ out) {
    int t = (int)(blockIdx.x * blockDim.x + threadIdx.x);
    int b = t >> 6, lane = t & 63;
    if (b >= BATCH) return;
    float p = accs[(size_t)b * EDIM + lane] * accs[(size_t)(BATCH + b) * EDIM + lane];
    #pragma unroll
    for (int off = 32; off; off >>= 1) p += __shfl_down(p, off, 64);
    if (lane == 0) out[b] = p * (1.0f / 16.0f);
}

extern "C" void kernel_launch(void* const* d_in, const int* in_sizes, int n_in,
                              void* d_out, int out_size, void* d_ws, size_t ws_size,
                              hipStream_t stream) {
    const float* emb   = (const float*)d_in[0];
    const int*   edge  = (const int*)d_in[1];
    const int*   src   = edge;            // edge_index[0]
    const int*   dst   = edge + NEDGES;   // edge_index[1]
    const int*   users = (const int*)d_in[2];
    const int*   items = (const int*)d_in[3];
    float*       out   = (float*)d_out;

    const size_t bufBytes = (size_t)NNODES * EDIM * sizeof(float); // 76.8 MB

    // workspace layout (zero-region is contiguous: one memset)
    size_t off = 0;
    float* bufA = (float*)((char*)d_ws + off); off = align256(off + bufBytes);
    float* bufB = (float*)((char*)d_ws + off); off = align256(off + bufBytes);
    float* accs = (float*)((char*)d_ws + off); off = align256(off + (size_t)2 * BATCH * EDIM * sizeof(float));
    int* row_ptr = (int*)((char*)d_ws + off); off = align256(off + (size_t)(NNODES + 1) * sizeof(int));
    int* ssrc    = (int*)((char*)d_ws + off); off = align256(off + (size_t)NEDGES * sizeof(int));
    int* epos    = (int*)((char*)d_ws + off); off = align256(off + (size_t)NEDGES * sizeof(int));
    int* wl1     = (int*)((char*)d_ws + off); off = align256(off + (size_t)NNODES * sizeof(int));
    int* wl2     = (int*)((char*)d_ws + off); off = align256(off + (size_t)NNODES * sizeof(int));
    int* cnt1    = (int*)((char*)d_ws + off); off = align256(off + (size_t)NBLKN * sizeof(int));
    int* cnt2    = (int*)((char*)d_ws + off); off = align256(off + (size_t)NBLKN * sizeof(int));
    int* wl_n    = (int*)((char*)d_ws + off); off = align256(off + 2 * sizeof(int));
    int* chunk_tot = (int*)((char*)d_ws + off); off = align256(off + (size_t)NCHUNKS * sizeof(int));
    const size_t zeroBase = off;
    int* counts    = (int*)((char*)d_ws + off); off += (size_t)NNODES * sizeof(int);
    unsigned char* mS = (unsigned char*)((char*)d_ws + off); off += (size_t)NNODES;
    unsigned char* mA = (unsigned char*)((char*)d_ws + off); off += (size_t)NNODES;
    unsigned char* mB = (unsigned char*)((char*)d_ws + off); off += (size_t)NNODES;
    const size_t zeroBytes = off - zeroBase;
    const size_t needed = align256(off);

    const dim3 blk(256);
    const int edgeBlocks = (NEDGES + 255) / 256;
    const int nodeBlocks = NBLKN;
    const int sampBlocks = (2 * BATCH * 64 + 255) / 256;
    const int dotBlocks  = (BATCH * 64 + 255) / 256;

    if (ws_size >= needed) {
        hipMemsetAsync((char*)d_ws + zeroBase, 0, zeroBytes, stream);
        mark_sampled_k<<<(2 * BATCH + 255) / 256, blk, 0, stream>>>(users, items, mS);
        hist_epos_k<<<edgeBlocks, blk, 0, stream>>>(src, dst, counts, epos, mS, mA);
        scan_chunk_k<<<NCHUNKS, blk, 0, stream>>>(counts, row_ptr, chunk_tot);
        scan_tops_k<<<1, 64, 0, stream>>>(chunk_tot, row_ptr);
        add_off_k<<<nodeBlocks, blk, 0, stream>>>(row_ptr, chunk_tot);
        scatter_fill_k<<<edgeBlocks, blk, 0, stream>>>(src, dst, row_ptr, epos, ssrc, mS, mA, mB);
        count_wl_k<<<nodeBlocks, blk, 0, stream>>>(mS, mA, mB, cnt1, cnt2);
        scan_blocks_k<<<1, 64, 0, stream>>>(cnt1, cnt2, wl_n);
        emit_wl_k<<<nodeBlocks, blk, 0, stream>>>(mS, mA, mB, cnt1, cnt2, wl1, wl2);

        prop_f4_k<<<PROP_BLOCKS, blk, 0, stream>>>(emb,  bufA, row_ptr, ssrc, wl1, wl_n);      // layer 1
        prop_f4_k<<<PROP_BLOCKS, blk, 0, stream>>>(bufA, bufB, row_ptr, ssrc, wl2, wl_n + 1);  // layer 2
        final_dot_k<<<dotBlocks, blk, 0, stream>>>(emb, bufA, bufB, users, items, row_ptr, ssrc, out);
    } else {
        // ---- fallback: baseline atomic path ----
        const int scatterBlocks = (NEDGES + 3) / 4;
        acc_batch_k<<<sampBlocks, blk, 0, stream>>>(emb, users, items, accs, 1);
        const float* cur = emb;
        float* bufs[2] = {bufA, bufB};
        for (int l = 0; l < 3; ++l) {
            float* nxt = bufs[l & 1];
            hipMemsetAsync(nxt, 0, bufBytes, stream);
            scatter_add_k<<<scatterBlocks, blk, 0, stream>>>(cur, nxt, src, dst);
            acc_batch_k<<<sampBlocks, blk, 0, stream>>>(nxt, users, items, accs, 0);
            cur = nxt;
        }
        dot_out_k<<<dotBlocks, blk, 0, stream>>>(accs, out);
    }
}

// Round 13
// 161.859 us; speedup vs baseline: 1.7676x; 1.0173x over previous
//
#include <hip/hip_runtime.h>

#define NUM_USERS 100000
#define NUM_ITEMS 200000
#define NNODES    300000   // NUM_USERS + NUM_ITEMS
#define EDIM      64
#define NEDGES    1200000
#define BATCH     4096
#define CHUNK     1024
#define NCHUNKS   ((NNODES + CHUNK - 1) / CHUNK)   // 293
#define NBLKN     ((NNODES + 255) / 256)           // 1172 node-blocks

static inline size_t align256(size_t x) { return (x + 255) & ~(size_t)255; }

__device__ __forceinline__ void f4add(float4& a, const float4& b) {
    a.x += b.x; a.y += b.y; a.z += b.z; a.w += b.w;
}

// ---------------- marking + CSR build ----------------

__global__ void mark_sampled_k(const int* __restrict__ users, const int* __restrict__ items,
                               unsigned char* __restrict__ mS) {
    int t = (int)(blockIdx.x * blockDim.x + threadIdx.x);
    if (t >= 2 * BATCH) return;
    int node = (t < BATCH) ? users[t] : (NUM_USERS + items[t - BATCH]);
    mS[node] = 1;
}

// Pass 1 over edges: histogram counts[dst] (KEEP the returned rank as epos[e])
// + markA (mA[src]=1 if dst sampled).
__global__ void hist_epos_k(const int* __restrict__ src, const int* __restrict__ dst,
                            int* __restrict__ counts, int* __restrict__ epos,
                            const unsigned char* __restrict__ mS, unsigned char* __restrict__ mA) {
    int e = (int)(blockIdx.x * blockDim.x + threadIdx.x);
    if (e >= NEDGES) return;
    int d = dst[e];
    epos[e] = atomicAdd(&counts[d], 1);
    if (mS[d]) mA[src[e]] = 1;
}

__global__ void scan_chunk_k(const int* __restrict__ counts, int* __restrict__ row_ptr,
                             int* __restrict__ chunk_tot) {
    __shared__ int sm[256];
    int t = threadIdx.x;
    int base = (int)blockIdx.x * CHUNK + t * 4;
    int v0 = (base + 0 < NNODES) ? counts[base + 0] : 0;
    int v1 = (base + 1 < NNODES) ? counts[base + 1] : 0;
    int v2 = (base + 2 < NNODES) ? counts[base + 2] : 0;
    int v3 = (base + 3 < NNODES) ? counts[base + 3] : 0;
    int ts = v0 + v1 + v2 + v3;
    sm[t] = ts;
    __syncthreads();
    for (int off = 1; off < 256; off <<= 1) {
        int x = (t >= off) ? sm[t - off] : 0;
        __syncthreads();
        sm[t] += x;
        __syncthreads();
    }
    int run = sm[t] - ts;
    if (t == 255) chunk_tot[blockIdx.x] = sm[255];
    if (base + 0 < NNODES) row_ptr[base + 0] = run; run += v0;
    if (base + 1 < NNODES) row_ptr[base + 1] = run; run += v1;
    if (base + 2 < NNODES) row_ptr[base + 2] = run; run += v2;
    if (base + 3 < NNODES) row_ptr[base + 3] = run;
}

// 64-lane shfl scan of the 293 chunk totals (exclusive, in-place).
__global__ void scan_tops_k(int* __restrict__ chunk_tot, int* __restrict__ row_ptr) {
    int lane = threadIdx.x & 63;
    int carry = 0;
    for (int base = 0; base < NCHUNKS; base += 64) {
        int idx = base + lane;
        int v = (idx < NCHUNKS) ? chunk_tot[idx] : 0;
        int x = v;
        #pragma unroll
        for (int off = 1; off < 64; off <<= 1) {
            int t = __shfl_up(x, off, 64);
            if (lane >= off) x += t;
        }
        if (idx < NCHUNKS) chunk_tot[idx] = carry + x - v;   // exclusive
        carry += __shfl(x, 63, 64);
    }
    if (lane == 0) row_ptr[NNODES] = carry;
}

__global__ void add_off_k(int* __restrict__ row_ptr, const int* __restrict__ chunk_tot) {
    int i = (int)(blockIdx.x * blockDim.x + threadIdx.x);
    if (i < NNODES) row_ptr[i] += chunk_tot[i / CHUNK];
}

// Pass 2 over edges: pure scatter (position from epos, no atomics)
// + markB (mB[src]=1 if dst in mS|mA).
__global__ void scatter_fill_k(const int* __restrict__ src, const int* __restrict__ dst,
                               const int* __restrict__ row_ptr, const int* __restrict__ epos,
                               int* __restrict__ ssrc, const unsigned char* __restrict__ mS,
                               const unsigned char* __restrict__ mA, unsigned char* __restrict__ mB) {
    int e = (int)(blockIdx.x * blockDim.x + threadIdx.x);
    if (e >= NEDGES) return;
    int d = dst[e];
    int s = src[e];
    ssrc[row_ptr[d] + epos[e]] = s;
    if (mS[d] | mA[d]) mB[s] = 1;
}

// ---- scan-based worklist compaction (no shared counters; r8/r9 lesson) ----

__global__ void count_wl_k(const unsigned char* __restrict__ mS, const unsigned char* __restrict__ mA,
                           const unsigned char* __restrict__ mB, int* __restrict__ cnt1,
                           int* __restrict__ cnt2) {
    __shared__ int w1[4], w2[4];
    int i = (int)(blockIdx.x * blockDim.x + threadIdx.x);
    int lane = threadIdx.x & 63, wv = threadIdx.x >> 6;
    unsigned char s = 0, a = 0, b = 0;
    if (i < NNODES) { s = mS[i]; a = mA[i]; b = mB[i]; }
    bool p1 = (i < NNODES) && (s | a | b);
    bool p2 = (i < NNODES) && (s | a);
    unsigned long long b1 = __ballot(p1), b2 = __ballot(p2);
    if (lane == 0) { w1[wv] = __popcll(b1); w2[wv] = __popcll(b2); }
    __syncthreads();
    if (threadIdx.x == 0) {
        cnt1[blockIdx.x] = w1[0] + w1[1] + w1[2] + w1[3];
        cnt2[blockIdx.x] = w2[0] + w2[1] + w2[2] + w2[3];
    }
}

__global__ void scan_blocks_k(int* __restrict__ cnt1, int* __restrict__ cnt2, int* __restrict__ wl_n) {
    int lane = threadIdx.x & 63;
    int carry1 = 0, carry2 = 0;
    for (int base = 0; base < NBLKN; base += 64) {
        int idx = base + lane;
        int v1 = (idx < NBLKN) ? cnt1[idx] : 0;
        int v2 = (idx < NBLKN) ? cnt2[idx] : 0;
        int x1 = v1, x2 = v2;
        #pragma unroll
        for (int off = 1; off < 64; off <<= 1) {
            int t1 = __shfl_up(x1, off, 64);
            int t2 = __shfl_up(x2, off, 64);
            if (lane >= off) { x1 += t1; x2 += t2; }
        }
        if (idx < NBLKN) { cnt1[idx] = carry1 + x1 - v1; cnt2[idx] = carry2 + x2 - v2; }
        carry1 += __shfl(x1, 63, 64);
        carry2 += __shfl(x2, 63, 64);
    }
    if (lane == 0) { wl_n[0] = carry1; wl_n[1] = carry2; }
}

__global__ void emit_wl_k(const unsigned char* __restrict__ mS, const unsigned char* __restrict__ mA,
                          const unsigned char* __restrict__ mB, const int* __restrict__ cnt1,
                          const int* __restrict__ cnt2, int* __restrict__ wl1, int* __restrict__ wl2) {
    __shared__ int w1[4], w2[4];
    int i = (int)(blockIdx.x * blockDim.x + threadIdx.x);
    int lane = threadIdx.x & 63, wv = threadIdx.x >> 6;
    unsigned char s = 0, a = 0, b = 0;
    if (i < NNODES) { s = mS[i]; a = mA[i]; b = mB[i]; }
    bool p1 = (i < NNODES) && (s | a | b);
    bool p2 = (i < NNODES) && (s | a);
    unsigned long long b1 = __ballot(p1), b2 = __ballot(p2);
    if (lane == 0) { w1[wv] = __popcll(b1); w2[wv] = __popcll(b2); }
    __syncthreads();
    int off1 = 0, off2 = 0;
    for (int k = 0; k < wv; ++k) { off1 += w1[k]; off2 += w2[k]; }
    unsigned long long lt = (1ULL << lane) - 1;
    if (p1) wl1[cnt1[blockIdx.x] + off1 + __popcll(b1 & lt)] = i;
    if (p2) wl2[cnt2[blockIdx.x] + off2 + __popcll(b2 & lt)] = i;
}

// ------- propagation: DUAL-node pipeline, 4 gather streams + prefetch -------

#define PROP_BLOCKS 2048   // 8192 waves

__global__ __launch_bounds__(256) void prop_f4_k(
        const float* __restrict__ cur, float* __restrict__ nxt,
        const int* __restrict__ row_ptr, const int* __restrict__ ssrc,
        const int* __restrict__ wl, const int* __restrict__ n_ptr) {
    int lane = threadIdx.x & 63;
    int sub = lane >> 4, d16 = lane & 15;
    int gw = (int)((blockIdx.x * blockDim.x + threadIdx.x) >> 6);
    int nw = (int)((gridDim.x * blockDim.x) >> 6);
    int n = *n_ptr;
    int nhalf = (n + 1) >> 1;
    const float4* cur4 = (const float4*)cur;
    if (gw >= nhalf) return;

    // stream A walks [gw, nhalf); stream B walks [gw+nhalf, n)
    int i = gw;
    int nodeA = wl[i];
    int nodeB = (i + nhalf < n) ? wl[i + nhalf] : -1;
    int a0 = row_ptr[nodeA], a1 = row_ptr[nodeA + 1];
    int b0 = 0, b1 = 0;
    if (nodeB >= 0) { b0 = row_ptr[nodeB]; b1 = row_ptr[nodeB + 1]; }
    int iaA = (a0 + sub     < a1) ? ssrc[a0 + sub]     : -1;
    int ibA = (a0 + 4 + sub < a1) ? ssrc[a0 + 4 + sub] : -1;
    int iaB = (b0 + sub     < b1) ? ssrc[b0 + sub]     : -1;
    int ibB = (b0 + 4 + sub < b1) ? ssrc[b0 + 4 + sub] : -1;

    while (true) {
        // prefetch next iteration's descriptors for BOTH streams
        int j = i + nw;
        bool have_next = (j < nhalf);
        int nnA = 0, nnB = -1, na0 = 0, na1 = 0, nb0 = 0, nb1 = 0;
        int niaA = -1, nibA = -1, niaB = -1, nibB = -1;
        if (have_next) {
            nnA = wl[j];
            nnB = (j + nhalf < n) ? wl[j + nhalf] : -1;
            na0 = row_ptr[nnA]; na1 = row_ptr[nnA + 1];
            if (nnB >= 0) { nb0 = row_ptr[nnB]; nb1 = row_ptr[nnB + 1]; }
            niaA = (na0 + sub     < na1) ? ssrc[na0 + sub]     : -1;
            nibA = (na0 + 4 + sub < na1) ? ssrc[na0 + 4 + sub] : -1;
            niaB = (nb0 + sub     < nb1) ? ssrc[nb0 + sub]     : -1;
            nibB = (nb0 + 4 + sub < nb1) ? ssrc[nb0 + 4 + sub] : -1;
        }
        // gather both nodes: 4 independent row streams
        float4 aA0 = {0.f,0.f,0.f,0.f}, aA1 = {0.f,0.f,0.f,0.f};
        float4 aB0 = {0.f,0.f,0.f,0.f}, aB1 = {0.f,0.f,0.f,0.f};
        if (iaA >= 0) f4add(aA0, cur4[(size_t)iaA * 16 + d16]);
        if (ibA >= 0) f4add(aA1, cur4[(size_t)ibA * 16 + d16]);
        if (iaB >= 0) f4add(aB0, cur4[(size_t)iaB * 16 + d16]);
        if (ibB >= 0) f4add(aB1, cur4[(size_t)ibB * 16 + d16]);
        for (int e = a0 + 8; e < a1; e += 8) {     // rare: deg > 8
            int p = e + sub, q = e + 4 + sub;
            if (p < a1) f4add(aA0, cur4[(size_t)ssrc[p] * 16 + d16]);
            if (q < a1) f4add(aA1, cur4[(size_t)ssrc[q] * 16 + d16]);
        }
        for (int e = b0 + 8; e < b1; e += 8) {
            int p = e + sub, q = e + 4 + sub;
            if (p < b1) f4add(aB0, cur4[(size_t)ssrc[p] * 16 + d16]);
            if (q < b1) f4add(aB1, cur4[(size_t)ssrc[q] * 16 + d16]);
        }
        f4add(aA0, aA1);
        aA0.x += __shfl_xor(aA0.x, 16, 64); aA0.x += __shfl_xor(aA0.x, 32, 64);
        aA0.y += __shfl_xor(aA0.y, 16, 64); aA0.y += __shfl_xor(aA0.y, 32, 64);
        aA0.z += __shfl_xor(aA0.z, 16, 64); aA0.z += __shfl_xor(aA0.z, 32, 64);
        aA0.w += __shfl_xor(aA0.w, 16, 64); aA0.w += __shfl_xor(aA0.w, 32, 64);
        if (sub == 0) ((float4*)nxt)[(size_t)nodeA * 16 + d16] = aA0;
        if (nodeB >= 0) {
            f4add(aB0, aB1);
            aB0.x += __shfl_xor(aB0.x, 16, 64); aB0.x += __shfl_xor(aB0.x, 32, 64);
            aB0.y += __shfl_xor(aB0.y, 16, 64); aB0.y += __shfl_xor(aB0.y, 32, 64);
            aB0.z += __shfl_xor(aB0.z, 16, 64); aB0.z += __shfl_xor(aB0.z, 32, 64);
            aB0.w += __shfl_xor(aB0.w, 16, 64); aB0.w += __shfl_xor(aB0.w, 32, 64);
            if (sub == 0) ((float4*)nxt)[(size_t)nodeB * 16 + d16] = aB0;
        }
        if (!have_next) break;
        i = j;
        nodeA = nnA; nodeB = nnB;
        a0 = na0; a1 = na1; b0 = nb0; b1 = nb1;
        iaA = niaA; ibA = nibA; iaB = niaB; ibB = nibB;
    }
}

// ---------------- fused layer-3 + layer-sum + dot (one wave per batch pair) ----------------

__device__ __forceinline__ float4 gather_row_sum(const float4* __restrict__ b4,
                                                 const int* __restrict__ ssrc,
                                                 int s0, int s1, int sub, int d16) {
    float4 acc0 = {0.f, 0.f, 0.f, 0.f}, acc1 = {0.f, 0.f, 0.f, 0.f};
    for (int e = s0; e < s1; e += 8) {
        int p = e + sub, q = e + 4 + sub;
        if (p < s1) f4add(acc0, b4[(size_t)ssrc[p] * 16 + d16]);
        if (q < s1) f4add(acc1, b4[(size_t)ssrc[q] * 16 + d16]);
    }
    f4add(acc0, acc1);
    return acc0;
}

__global__ __launch_bounds__(256) void final_dot_k(
        const float* __restrict__ emb, const float* __restrict__ bufA,
        const float* __restrict__ bufB, const int* __restrict__ users,
        const int* __restrict__ items, const int* __restrict__ row_ptr,
        const int* __restrict__ ssrc, float* __restrict__ out) {
    int t = (int)(blockIdx.x * blockDim.x + threadIdx.x);
    int b = t >> 6;
    if (b >= BATCH) return;
    int lane = threadIdx.x & 63, sub = lane >> 4, d16 = lane & 15;
    int nu = users[b], ni = NUM_USERS + items[b];
    int u0 = row_ptr[nu], u1 = row_ptr[nu + 1];
    int i0 = row_ptr[ni], i1 = row_ptr[ni + 1];
    const float4* b4 = (const float4*)bufB;
    float4 au = gather_row_sum(b4, ssrc, u0, u1, sub, d16);   // layer-3 @ user
    float4 ai = gather_row_sum(b4, ssrc, i0, i1, sub, d16);   // layer-3 @ item
    au.x += __shfl_xor(au.x, 16, 64); au.x += __shfl_xor(au.x, 32, 64);
    au.y += __shfl_xor(au.y, 16, 64); au.y += __shfl_xor(au.y, 32, 64);
    au.z += __shfl_xor(au.z, 16, 64); au.z += __shfl_xor(au.z, 32, 64);
    au.w += __shfl_xor(au.w, 16, 64); au.w += __shfl_xor(au.w, 32, 64);
    ai.x += __shfl_xor(ai.x, 16, 64); ai.x += __shfl_xor(ai.x, 32, 64);
    ai.y += __shfl_xor(ai.y, 16, 64); ai.y += __shfl_xor(ai.y, 32, 64);
    ai.z += __shfl_xor(ai.z, 16, 64); ai.z += __shfl_xor(ai.z, 32, 64);
    ai.w += __shfl_xor(ai.w, 16, 64); ai.w += __shfl_xor(ai.w, 32, 64);
    if (sub == 0) {
        size_t ru = (size_t)nu * 16 + d16, ri = (size_t)ni * 16 + d16;
        float4 eu = ((const float4*)emb)[ru], pu = ((const float4*)bufA)[ru], qu = ((const float4*)bufB)[ru];
        float4 ei = ((const float4*)emb)[ri], pi = ((const float4*)bufA)[ri], qi = ((const float4*)bufB)[ri];
        float fx = (eu.x + pu.x + qu.x + au.x) * (ei.x + pi.x + qi.x + ai.x);
        float fy = (eu.y + pu.y + qu.y + au.y) * (ei.y + pi.y + qi.y + ai.y);
        float fz = (eu.z + pu.z + qu.z + au.z) * (ei.z + pi.z + qi.z + ai.z);
        float fw = (eu.w + pu.w + qu.w + au.w) * (ei.w + pi.w + qi.w + ai.w);
        float p = fx + fy + fz + fw;
        p += __shfl_xor(p, 1, 64); p += __shfl_xor(p, 2, 64);
        p += __shfl_xor(p, 4, 64); p += __shfl_xor(p, 8, 64);
        if (d16 == 0) out[b] = p * (1.0f / 16.0f);
    }
}

// ---------------- fallback (baseline atomic path) ----------------

__global__ void acc_batch_k(const float* __restrict__ cur, const int* __restrict__ users,
                            const int* __restrict__ items, float* __restrict__ accs, int first) {
    int t = (int)(blockIdx.x * blockDim.x + threadIdx.x);
    int row = t >> 6, lane = t & 63;
    if (row >= 2 * BATCH) return;
    int node = (row < BATCH) ? users[row] : (NUM_USERS + items[row - BATCH]);
    float v = cur[(size_t)node * EDIM + lane];
    size_t o = (size_t)row * EDIM + lane;
    if (first) accs[o] = v;
    else       accs[o] += v;
}

__global__ void scatter_add_k(const float* __restrict__ cur, float* __restrict__ nxt,
                              const int* __restrict__ src, const int* __restrict__ dst) {
    int w = (int)((blockIdx.x * blockDim.x + threadIdx.x) >> 6);
    int lane = threadIdx.x & 63;
    if (w >= NEDGES) return;
    float v = cur[(size_t)src[w] * EDIM + lane];
    atomicAdd(&nxt[(size_t)dst[w] * EDIM + lane], v);
}

__global__ void dot_out_k(const float* __restrict__ accs, float* __restrict__ out) {
    int t = (int)(blockIdx.x * blockDim.x + threadIdx.x);
    int b = t >> 6, lane = t & 63;
    if (b >= BATCH) return;
    float p = accs[(size_t)b * EDIM + lane] * accs[(size_t)(BATCH + b) * EDIM + lane];
    #pragma unroll
    for (int off = 32; off; off >>= 1) p += __shfl_down(p, off, 64);
    if (lane == 0) out[b] = p * (1.0f / 16.0f);
}

extern "C" void kernel_launch(void* const* d_in, const int* in_sizes, int n_in,
                              void* d_out, int out_size, void* d_ws, size_t ws_size,
                              hipStream_t stream) {
    const float* emb   = (const float*)d_in[0];
    const int*   edge  = (const int*)d_in[1];
    const int*   src   = edge;            // edge_index[0]
    const int*   dst   = edge + NEDGES;   // edge_index[1]
    const int*   users = (const int*)d_in[2];
    const int*   items = (const int*)d_in[3];
    float*       out   = (float*)d_out;

    const size_t bufBytes = (size_t)NNODES * EDIM * sizeof(float); // 76.8 MB

    // workspace layout (zero-region is contiguous: one memset)
    size_t off = 0;
    float* bufA = (float*)((char*)d_ws + off); off = align256(off + bufBytes);
    float* bufB = (float*)((char*)d_ws + off); off = align256(off + bufBytes);
    float* accs = (float*)((char*)d_ws + off); off = align256(off + (size_t)2 * BATCH * EDIM * sizeof(float));
    int* row_ptr = (int*)((char*)d_ws + off); off = align256(off + (size_t)(NNODES + 1) * sizeof(int));
    int* ssrc    = (int*)((char*)d_ws + off); off = align256(off + (size_t)NEDGES * sizeof(int));
    int* epos    = (int*)((char*)d_ws + off); off = align256(off + (size_t)NEDGES * sizeof(int));
    int* wl1     = (int*)((char*)d_ws + off); off = align256(off + (size_t)NNODES * sizeof(int));
    int* wl2     = (int*)((char*)d_ws + off); off = align256(off + (size_t)NNODES * sizeof(int));
    int* cnt1    = (int*)((char*)d_ws + off); off = align256(off + (size_t)NBLKN * sizeof(int));
    int* cnt2    = (int*)((char*)d_ws + off); off = align256(off + (size_t)NBLKN * sizeof(int));
    int* wl_n    = (int*)((char*)d_ws + off); off = align256(off + 2 * sizeof(int));
    int* chunk_tot = (int*)((char*)d_ws + off); off = align256(off + (size_t)NCHUNKS * sizeof(int));
    const size_t zeroBase = off;
    int* counts    = (int*)((char*)d_ws + off); off += (size_t)NNODES * sizeof(int);
    unsigned char* mS = (unsigned char*)((char*)d_ws + off); off += (size_t)NNODES;
    unsigned char* mA = (unsigned char*)((char*)d_ws + off); off += (size_t)NNODES;
    unsigned char* mB = (unsigned char*)((char*)d_ws + off); off += (size_t)NNODES;
    const size_t zeroBytes = off - zeroBase;
    const size_t needed = align256(off);

    const dim3 blk(256);
    const int edgeBlocks = (NEDGES + 255) / 256;
    const int nodeBlocks = NBLKN;
    const int sampBlocks = (2 * BATCH * 64 + 255) / 256;
    const int dotBlocks  = (BATCH * 64 + 255) / 256;

    if (ws_size >= needed) {
        hipMemsetAsync((char*)d_ws + zeroBase, 0, zeroBytes, stream);
        mark_sampled_k<<<(2 * BATCH + 255) / 256, blk, 0, stream>>>(users, items, mS);
        hist_epos_k<<<edgeBlocks, blk, 0, stream>>>(src, dst, counts, epos, mS, mA);
        scan_chunk_k<<<NCHUNKS, blk, 0, stream>>>(counts, row_ptr, chunk_tot);
        scan_tops_k<<<1, 64, 0, stream>>>(chunk_tot, row_ptr);
        add_off_k<<<nodeBlocks, blk, 0, stream>>>(row_ptr, chunk_tot);
        scatter_fill_k<<<edgeBlocks, blk, 0, stream>>>(src, dst, row_ptr, epos, ssrc, mS, mA, mB);
        count_wl_k<<<nodeBlocks, blk, 0, stream>>>(mS, mA, mB, cnt1, cnt2);
        scan_blocks_k<<<1, 64, 0, stream>>>(cnt1, cnt2, wl_n);
        emit_wl_k<<<nodeBlocks, blk, 0, stream>>>(mS, mA, mB, cnt1, cnt2, wl1, wl2);

        prop_f4_k<<<PROP_BLOCKS, blk, 0, stream>>>(emb,  bufA, row_ptr, ssrc, wl1, wl_n);      // layer 1
        prop_f4_k<<<PROP_BLOCKS, blk, 0, stream>>>(bufA, bufB, row_ptr, ssrc, wl2, wl_n + 1);  // layer 2
        final_dot_k<<<dotBlocks, blk, 0, stream>>>(emb, bufA, bufB, users, items, row_ptr, ssrc, out);
    } else {
        // ---- fallback: baseline atomic path ----
        const int scatterBlocks = (NEDGES + 3) / 4;
        acc_batch_k<<<sampBlocks, blk, 0, stream>>>(emb, users, items, accs, 1);
        const float* cur = emb;
        float* bufs[2] = {bufA, bufB};
        for (int l = 0; l < 3; ++l) {
            float* nxt = bufs[l & 1];
            hipMemsetAsync(nxt, 0, bufBytes, stream);
            scatter_add_k<<<scatterBlocks, blk, 0, stream>>>(cur, nxt, src, dst);
            acc_batch_k<<<sampBlocks, blk, 0, stream>>>(nxt, users, items, accs, 0);
            cur = nxt;
        }
        dot_out_k<<<dotBlocks, blk, 0, stream>>>(accs, out);
    }
}